// Round 5
// baseline (647.870 us; speedup 1.0000x reference)
//
#include <hip/hip_runtime.h>

namespace {

constexpr int B = 16;
constexpr int N = 1024;
constexpr int K = 20;
constexpr int HID = 128;
constexpr float BOX = 10.0f;

__device__ __forceinline__ float tanh_f(float x) {
    // tanh(x) = 1 - 2/(exp(2x)+1); __expf rel-err ~1e-6 << 2% threshold
    float e = __expf(2.0f * x);
    return 1.0f - 2.0f / (e + 1.0f);
}

// One block per particle: 20-NN selection + 78 features + 2-layer MLP +
// maxpool + energy. No global scratch (all intermediates in LDS/registers).
__global__ __launch_bounds__(256) void fused_kernel(
    const float* __restrict__ pos, const float* __restrict__ ori,
    const float* __restrict__ w1, const float* __restrict__ b1,
    const float* __restrict__ w2, const float* __restrict__ b2,
    const float* __restrict__ w3, const float* __restrict__ b3,
    float* __restrict__ out)    // <-- reference output dtype is FLOAT32
{
    // float4-typed LDS => guaranteed 16B alignment for b128 reads
    __shared__ float4 fS4[K][20];     // 20 rows x 80 floats (78 feats + 2 zero-pad)
    __shared__ float4 h1S4[K][HID / 4];
    __shared__ float4 h2S4[K][HID / 4];
    __shared__ float wr2[4];
    __shared__ int   wid[4];
    __shared__ int   nbrS[K];
    __shared__ float RpS[9];
    __shared__ float red[2];

    const int pid = blockIdx.x;            // b*1024 + n
    const int b = pid >> 10;
    const int n = pid & (N - 1);
    const int t = threadIdx.x;
    const float* posb = pos + (size_t)b * N * 3;
    const float* orib = ori + (size_t)b * N * 9;

    if (t < 9) RpS[t] = orib[(size_t)n * 9 + t];   // visible after first barrier

    const float xi = posb[n * 3 + 0];
    const float yi = posb[n * 3 + 1];
    const float zi = posb[n * 3 + 2];

    // ---- phase 1: all-pairs r2 (4 candidates/thread), min-image PBC ----
    // explicit round-to-nearest ops (no fma contraction) to match numpy f32
    float r2v[4];
    int   idv[4];
#pragma unroll
    for (int q = 0; q < 4; ++q) {
        const int j = t + q * 256;
        float dx = __fsub_rn(xi, posb[j * 3 + 0]);
        float dy = __fsub_rn(yi, posb[j * 3 + 1]);
        float dz = __fsub_rn(zi, posb[j * 3 + 2]);
        dx = __fsub_rn(dx, __fmul_rn(BOX, rintf(__fdiv_rn(dx, BOX))));
        dy = __fsub_rn(dy, __fmul_rn(BOX, rintf(__fdiv_rn(dy, BOX))));
        dz = __fsub_rn(dz, __fmul_rn(BOX, rintf(__fdiv_rn(dz, BOX))));
        float r2 = __fadd_rn(__fadd_rn(__fmul_rn(dx, dx), __fmul_rn(dy, dy)),
                             __fmul_rn(dz, dz));
        if (j == n) r2 = 1e9f;             // ref adds eye*1e9 (self always excluded)
        r2v[q] = r2;
        idv[q] = j;
    }

    // ---- phase 2: iterative 20x argmin (lexicographic (r2, idx) min) ----
    for (int kk = 0; kk < K; ++kk) {
        float best = r2v[0];
        int   bi   = idv[0];
#pragma unroll
        for (int q = 1; q < 4; ++q) {
            if (r2v[q] < best || (r2v[q] == best && idv[q] < bi)) {
                best = r2v[q]; bi = idv[q];
            }
        }
        // wave butterfly allreduce: float + int shuffles only
#pragma unroll
        for (int m = 1; m < 64; m <<= 1) {
            const float or2 = __shfl_xor(best, m, 64);
            const int   oid = __shfl_xor(bi,   m, 64);
            if (or2 < best || (or2 == best && oid < bi)) { best = or2; bi = oid; }
        }
        if ((t & 63) == 0) { wr2[t >> 6] = best; wid[t >> 6] = bi; }
        __syncthreads();
        float gb = wr2[0];
        int   gi = wid[0];
#pragma unroll
        for (int w = 1; w < 4; ++w) {
            if (wr2[w] < gb || (wr2[w] == gb && wid[w] < gi)) {
                gb = wr2[w]; gi = wid[w];
            }
        }
        if (t == 0) nbrS[kk] = gi;
#pragma unroll
        for (int q = 0; q < 4; ++q) if (idv[q] == gi) r2v[q] = 3e38f;  // mask selected
        __syncthreads();                   // protects wr2/wid/nbrS for next round
    }

    // ---- phase 3: features, lane k < 20 builds the full 78-vector ----
    if (t < K) {
        const int j = nbrS[t];
        float Rp[9], Rn[9];
#pragma unroll
        for (int q = 0; q < 9; ++q) Rp[q] = RpS[q];
#pragma unroll
        for (int q = 0; q < 9; ++q) Rn[q] = orib[(size_t)j * 9 + q];

        float dx = __fsub_rn(xi, posb[j * 3 + 0]);
        float dy = __fsub_rn(yi, posb[j * 3 + 1]);
        float dz = __fsub_rn(zi, posb[j * 3 + 2]);
        dx = __fsub_rn(dx, __fmul_rn(BOX, rintf(__fdiv_rn(dx, BOX))));
        dy = __fsub_rn(dy, __fmul_rn(BOX, rintf(__fdiv_rn(dy, BOX))));
        dz = __fsub_rn(dz, __fmul_rn(BOX, rintf(__fdiv_rn(dz, BOX))));
        const float r2 = __fadd_rn(__fadd_rn(__fmul_rn(dx, dx), __fmul_rn(dy, dy)),
                                   __fmul_rn(dz, dz));
        const float r = sqrtf(r2);
        const float invr = 1.0f / r;
        const float ux = dx / r, uy = dy / r, uz = dz / r;

        float* f = (float*)&fS4[t][0];
        f[0] = r;                          // NN_R
        f[1] = invr;                       // inv_r
        f[2] = ux; f[3] = uy; f[4] = uz;   // u

        // dot[i][l]=Rp_row_i . Rn_row_l -> f[5+i*3+l]
        // elem[i][l][m]=Rp[i][m]*Rn[l][m] -> f[14+i*9+l*3+m]
        // elem_norm -> f[41+i*3+l];  rel=(Rp^T Rn)[i][l] -> f[62+i*3+l]
#pragma unroll
        for (int i = 0; i < 3; ++i) {
#pragma unroll
            for (int l = 0; l < 3; ++l) {
                float s = 0.0f, en2 = 0.0f;
#pragma unroll
                for (int m = 0; m < 3; ++m) {
                    const float e = Rp[i * 3 + m] * Rn[l * 3 + m];
                    f[14 + i * 9 + l * 3 + m] = e;
                    en2 += e * e;
                    s += e;
                }
                f[5 + i * 3 + l] = s;
                f[41 + i * 3 + l] = sqrtf(en2);
                float rr = 0.0f;
#pragma unroll
                for (int m = 0; m < 3; ++m) rr += Rp[m * 3 + i] * Rn[m * 3 + l];
                f[62 + i * 3 + l] = rr;
            }
        }
        // cross of corresponding axes -> f[50+i*3+c]; norm -> f[59+i]
        // rbf_p -> f[71+i]; rbf_n -> f[74+i]
#pragma unroll
        for (int i = 0; i < 3; ++i) {
            const float ax = Rp[i * 3 + 0], ay = Rp[i * 3 + 1], az = Rp[i * 3 + 2];
            const float bx = Rn[i * 3 + 0], by = Rn[i * 3 + 1], bz = Rn[i * 3 + 2];
            const float cx = ay * bz - az * by;
            const float cy = az * bx - ax * bz;
            const float cz = ax * by - ay * bx;
            f[50 + i * 3 + 0] = cx;
            f[50 + i * 3 + 1] = cy;
            f[50 + i * 3 + 2] = cz;
            f[59 + i] = sqrtf(cx * cx + cy * cy + cz * cz);
            const float dp = ux * ax + uy * ay + uz * az;
            f[71 + i] = __expf(-dp * dp);
            const float dn = ux * bx + uy * by + uz * bz;
            f[74 + i] = __expf(-dn * dn);
        }
        const float tr = f[62] + f[66] + f[70];
        float ca = (tr - 1.0f) * 0.5f;
        ca = fminf(fmaxf(ca, -1.0f + 1e-6f), 1.0f - 1e-6f);
        f[77] = acosf(ca);                 // angle
        f[78] = 0.0f;                      // pad (zero weight contribution)
        f[79] = 0.0f;
    }
    __syncthreads();

    // ---- phase 4: layer 1  h1[k][c] = tanh(f[k][:78] @ w1[:,c]) ----
    const int c = t & (HID - 1);
    const int half = t >> 7;               // wave-uniform: rows half*10..half*10+9
    float* const h1 = (float*)h1S4;
    float* const h2 = (float*)h2S4;

    float acc[10];
#pragma unroll
    for (int k = 0; k < 10; ++k) acc[k] = b1[c];
    for (int i4 = 0; i4 < 20; ++i4) {
        const int i = i4 * 4;
        const float wa = w1[(i + 0) * HID + c];
        const float wb = w1[(i + 1) * HID + c];
        const float wc = (i + 2 < 78) ? w1[(i + 2) * HID + c] : 0.0f;
        const float wd = (i + 3 < 78) ? w1[(i + 3) * HID + c] : 0.0f;
#pragma unroll
        for (int k = 0; k < 10; ++k) {
            const float4 fv = fS4[half * 10 + k][i4];
            acc[k] = fmaf(fv.x, wa, acc[k]);
            acc[k] = fmaf(fv.y, wb, acc[k]);
            acc[k] = fmaf(fv.z, wc, acc[k]);
            acc[k] = fmaf(fv.w, wd, acc[k]);
        }
    }
#pragma unroll
    for (int k = 0; k < 10; ++k) h1[(half * 10 + k) * HID + c] = tanh_f(acc[k]);
    __syncthreads();

    // ---- phase 5: layer 2  h2[k][c] = tanh(h1[k][:] @ w2[:,c]) ----
#pragma unroll
    for (int k = 0; k < 10; ++k) acc[k] = b2[c];
    for (int i4 = 0; i4 < HID / 4; ++i4) {
        const int i = i4 * 4;
        const float wa = w2[(i + 0) * HID + c];
        const float wb = w2[(i + 1) * HID + c];
        const float wc = w2[(i + 2) * HID + c];
        const float wd = w2[(i + 3) * HID + c];
#pragma unroll
        for (int k = 0; k < 10; ++k) {
            const float4 fv = h1S4[half * 10 + k][i4];
            acc[k] = fmaf(fv.x, wa, acc[k]);
            acc[k] = fmaf(fv.y, wb, acc[k]);
            acc[k] = fmaf(fv.z, wc, acc[k]);
            acc[k] = fmaf(fv.w, wd, acc[k]);
        }
    }
#pragma unroll
    for (int k = 0; k < 10; ++k) h2[(half * 10 + k) * HID + c] = tanh_f(acc[k]);
    __syncthreads();

    // ---- phase 6: maxpool over K, dot w3, wave reduce, f32 store ----
    if (t < HID) {
        float m = h2[t];
#pragma unroll
        for (int k = 1; k < K; ++k) m = fmaxf(m, h2[k * HID + t]);
        float v = m * w3[t];
#pragma unroll
        for (int off = 32; off > 0; off >>= 1) v += __shfl_down(v, off, 64);
        if ((t & 63) == 0) red[t >> 6] = v;
    }
    __syncthreads();
    if (t == 0) out[pid] = red[0] + red[1] + b3[0];
}

} // namespace

extern "C" void kernel_launch(void* const* d_in, const int* in_sizes, int n_in,
                              void* d_out, int out_size, void* d_ws, size_t ws_size,
                              hipStream_t stream) {
    const float* pos = (const float*)d_in[0];
    const float* ori = (const float*)d_in[1];
    const float* w1  = (const float*)d_in[2];
    const float* b1  = (const float*)d_in[3];
    const float* w2  = (const float*)d_in[4];
    const float* b2  = (const float*)d_in[5];
    const float* w3  = (const float*)d_in[6];
    const float* b3  = (const float*)d_in[7];
    float* out = (float*)d_out;            // f32 output per reference dtype

    fused_kernel<<<dim3(B * N), dim3(256), 0, stream>>>(
        pos, ori, w1, b1, w2, b2, w3, b3, out);
}

// Round 6
// 504.256 us; speedup vs baseline: 1.2848x; 1.2848x over previous
//
#include <hip/hip_runtime.h>
#include <hip/hip_bf16.h>

namespace {

constexpr int B = 16;
constexpr int N = 1024;
constexpr int K = 20;
constexpr int HID = 128;
constexpr float BOX = 10.0f;

constexpr int KP1 = 96;                 // layer-1 K padded 78 -> 96 (3 k-steps of 32)
constexpr int FP = 104;                 // fS row pitch (bf16): 2-way banks (free)
constexpr int H1P = 132;                // h1 row pitch (f32): 2-way banks (free)

typedef __attribute__((ext_vector_type(8))) short short8;   // 8 bf16 = 4 VGPR
typedef __attribute__((ext_vector_type(4))) float f32x4;

__device__ __forceinline__ float tanh_f(float x) {
    float e = __expf(2.0f * x);
    return 1.0f - 2.0f / (e + 1.0f);
}

__device__ __forceinline__ ushort bfb(float x) {
    __hip_bfloat16 h = __float2bfloat16(x);
    return __builtin_bit_cast(ushort, h);
}

// ---- weight preconversion: w1[78][128] -> w1T(hi/lo)[128][96] bf16 (transposed,
// K-padded); w2[128][128] -> w2T(hi/lo)[128][128]. hi+lo split => effectively f32
// weights through 2 MFMAs. Runs every launch (graph-safe, same work each call).
__global__ __launch_bounds__(256) void conv_w_kernel(
    const float* __restrict__ w1, const float* __restrict__ w2,
    ushort* __restrict__ w1Th, ushort* __restrict__ w1Tl,
    ushort* __restrict__ w2Th, ushort* __restrict__ w2Tl)
{
    const int idx = blockIdx.x * 256 + threadIdx.x;
    if (idx < 128 * KP1) {
        const int n = idx / KP1, k = idx - n * KP1;
        const float v = (k < 78) ? w1[k * HID + n] : 0.0f;
        const __hip_bfloat16 h = __float2bfloat16(v);
        w1Th[idx] = __builtin_bit_cast(ushort, h);
        w1Tl[idx] = bfb(v - __bfloat162float(h));
    } else if (idx < 128 * KP1 + 128 * 128) {
        const int i = idx - 128 * KP1;
        const int n = i >> 7, k = i & 127;
        const float v = w2[k * HID + n];
        const __hip_bfloat16 h = __float2bfloat16(v);
        w2Th[i] = __builtin_bit_cast(ushort, h);
        w2Tl[i] = bfb(v - __bfloat162float(h));
    }
}

// One block per particle: 20-NN + features + MFMA MLP + maxpool + energy.
__global__ __launch_bounds__(256) void fused_kernel(
    const float* __restrict__ pos, const float* __restrict__ ori,
    const float* __restrict__ b1, const float* __restrict__ b2,
    const float* __restrict__ w3, const float* __restrict__ b3,
    const ushort* __restrict__ w1Th, const ushort* __restrict__ w1Tl,
    const ushort* __restrict__ w2Th, const ushort* __restrict__ w2Tl,
    float* __restrict__ out)
{
    __shared__ __align__(16) __hip_bfloat16 fS[32][FP];  // rows 0-19 real, 20-31 don't-care
    __shared__ __align__(16) float h1S[32][H1P];
    __shared__ float wr2[4];
    __shared__ int   wid[4];
    __shared__ int   nbrS[K];
    __shared__ float RpS[9];
    __shared__ float red[4];

    const int pid = blockIdx.x;            // b*1024 + n
    const int b = pid >> 10;
    const int n = pid & (N - 1);
    const int t = threadIdx.x;
    const float* posb = pos + (size_t)b * N * 3;
    const float* orib = ori + (size_t)b * N * 9;

    if (t < 9) RpS[t] = orib[(size_t)n * 9 + t];   // visible after first barrier

    const float xi = posb[n * 3 + 0];
    const float yi = posb[n * 3 + 1];
    const float zi = posb[n * 3 + 2];

    // ---- phase 1: all-pairs r2 (4 candidates/thread), min-image PBC ----
    float r2v[4];
    int   idv[4];
#pragma unroll
    for (int q = 0; q < 4; ++q) {
        const int j = t + q * 256;
        float dx = __fsub_rn(xi, posb[j * 3 + 0]);
        float dy = __fsub_rn(yi, posb[j * 3 + 1]);
        float dz = __fsub_rn(zi, posb[j * 3 + 2]);
        dx = __fsub_rn(dx, __fmul_rn(BOX, rintf(__fdiv_rn(dx, BOX))));
        dy = __fsub_rn(dy, __fmul_rn(BOX, rintf(__fdiv_rn(dy, BOX))));
        dz = __fsub_rn(dz, __fmul_rn(BOX, rintf(__fdiv_rn(dz, BOX))));
        float r2 = __fadd_rn(__fadd_rn(__fmul_rn(dx, dx), __fmul_rn(dy, dy)),
                             __fmul_rn(dz, dz));
        if (j == n) r2 = 1e9f;
        r2v[q] = r2;
        idv[q] = j;
    }

    // ---- phase 2: iterative 20x argmin (lexicographic (r2, idx) min) ----
    for (int kk = 0; kk < K; ++kk) {
        float best = r2v[0];
        int   bi   = idv[0];
#pragma unroll
        for (int q = 1; q < 4; ++q) {
            if (r2v[q] < best || (r2v[q] == best && idv[q] < bi)) {
                best = r2v[q]; bi = idv[q];
            }
        }
#pragma unroll
        for (int m = 1; m < 64; m <<= 1) {
            const float or2 = __shfl_xor(best, m, 64);
            const int   oid = __shfl_xor(bi,   m, 64);
            if (or2 < best || (or2 == best && oid < bi)) { best = or2; bi = oid; }
        }
        if ((t & 63) == 0) { wr2[t >> 6] = best; wid[t >> 6] = bi; }
        __syncthreads();
        float gb = wr2[0];
        int   gi = wid[0];
#pragma unroll
        for (int w = 1; w < 4; ++w) {
            if (wr2[w] < gb || (wr2[w] == gb && wid[w] < gi)) {
                gb = wr2[w]; gi = wid[w];
            }
        }
        if (t == 0) nbrS[kk] = gi;
#pragma unroll
        for (int q = 0; q < 4; ++q) if (idv[q] == gi) r2v[q] = 3e38f;
        __syncthreads();
    }

    // ---- phase 3: features, lane k < 20 builds its 78-vector (bf16 to LDS) ----
    if (t < K) {
        const int j = nbrS[t];
        float Rp[9], Rn[9];
#pragma unroll
        for (int q = 0; q < 9; ++q) Rp[q] = RpS[q];
#pragma unroll
        for (int q = 0; q < 9; ++q) Rn[q] = orib[(size_t)j * 9 + q];

        float dx = __fsub_rn(xi, posb[j * 3 + 0]);
        float dy = __fsub_rn(yi, posb[j * 3 + 1]);
        float dz = __fsub_rn(zi, posb[j * 3 + 2]);
        dx = __fsub_rn(dx, __fmul_rn(BOX, rintf(__fdiv_rn(dx, BOX))));
        dy = __fsub_rn(dy, __fmul_rn(BOX, rintf(__fdiv_rn(dy, BOX))));
        dz = __fsub_rn(dz, __fmul_rn(BOX, rintf(__fdiv_rn(dz, BOX))));
        const float r2 = __fadd_rn(__fadd_rn(__fmul_rn(dx, dx), __fmul_rn(dy, dy)),
                                   __fmul_rn(dz, dz));
        const float r = sqrtf(r2);
        const float invr = 1.0f / r;
        const float ux = dx / r, uy = dy / r, uz = dz / r;

        __hip_bfloat16* f = fS[t];
        f[0] = __float2bfloat16(r);
        f[1] = __float2bfloat16(invr);
        f[2] = __float2bfloat16(ux);
        f[3] = __float2bfloat16(uy);
        f[4] = __float2bfloat16(uz);

        float diag[3];
#pragma unroll
        for (int i = 0; i < 3; ++i) {
#pragma unroll
            for (int l = 0; l < 3; ++l) {
                float s = 0.0f, en2 = 0.0f;
#pragma unroll
                for (int m = 0; m < 3; ++m) {
                    const float e = Rp[i * 3 + m] * Rn[l * 3 + m];
                    f[14 + i * 9 + l * 3 + m] = __float2bfloat16(e);
                    en2 += e * e;
                    s += e;
                }
                f[5 + i * 3 + l] = __float2bfloat16(s);
                f[41 + i * 3 + l] = __float2bfloat16(sqrtf(en2));
                float rr = 0.0f;
#pragma unroll
                for (int m = 0; m < 3; ++m) rr += Rp[m * 3 + i] * Rn[m * 3 + l];
                f[62 + i * 3 + l] = __float2bfloat16(rr);
                if (i == l) diag[i] = rr;
            }
        }
#pragma unroll
        for (int i = 0; i < 3; ++i) {
            const float ax = Rp[i * 3 + 0], ay = Rp[i * 3 + 1], az = Rp[i * 3 + 2];
            const float bx = Rn[i * 3 + 0], by = Rn[i * 3 + 1], bz = Rn[i * 3 + 2];
            const float cx = ay * bz - az * by;
            const float cy = az * bx - ax * bz;
            const float cz = ax * by - ay * bx;
            f[50 + i * 3 + 0] = __float2bfloat16(cx);
            f[50 + i * 3 + 1] = __float2bfloat16(cy);
            f[50 + i * 3 + 2] = __float2bfloat16(cz);
            f[59 + i] = __float2bfloat16(sqrtf(cx * cx + cy * cy + cz * cz));
            const float dp = ux * ax + uy * ay + uz * az;
            f[71 + i] = __float2bfloat16(__expf(-dp * dp));
            const float dn = ux * bx + uy * by + uz * bz;
            f[74 + i] = __float2bfloat16(__expf(-dn * dn));
        }
        const float tr = diag[0] + diag[1] + diag[2];
        float ca = (tr - 1.0f) * 0.5f;
        ca = fminf(fmaxf(ca, -1.0f + 1e-6f), 1.0f - 1e-6f);
        f[77] = __float2bfloat16(acosf(ca));
#pragma unroll
        for (int i = 78; i < KP1; ++i) f[i] = __float2bfloat16(0.0f);  // K-pad
    }
    __syncthreads();

    // ---- MFMA MLP: wave wv owns output cols [32wv, 32wv+32) ----
    // A-frag: row = lr (+16 for m-tile 1), k = ks*32 + lg*8 .. +8
    // B-frag: col n = lr (+tile base), same k slice (w*T stored [n][k])
    // C/D:    col = lr, row = lg*4 + reg (+16 for m-tile 1)
    const int wv = t >> 6, ln = t & 63;
    const int lr = ln & 15, lg = ln >> 4;
    const int n0 = wv * 32 + lr, n1 = n0 + 16;

    f32x4 acc00, acc01, acc10, acc11;       // [mtile][ntile]
    {
        const float bb0 = b1[n0], bb1 = b1[n1];
        acc00 = f32x4{bb0, bb0, bb0, bb0};  acc10 = acc00;
        acc01 = f32x4{bb1, bb1, bb1, bb1};  acc11 = acc01;
    }
    {
        const ushort* pb0h = w1Th + n0 * KP1 + lg * 8;
        const ushort* pb0l = w1Tl + n0 * KP1 + lg * 8;
        const ushort* pb1h = w1Th + n1 * KP1 + lg * 8;
        const ushort* pb1l = w1Tl + n1 * KP1 + lg * 8;
#pragma unroll
        for (int ks = 0; ks < 3; ++ks) {
            const short8 a0 = *reinterpret_cast<const short8*>(&fS[lr][ks * 32 + lg * 8]);
            const short8 a1 = *reinterpret_cast<const short8*>(&fS[16 + lr][ks * 32 + lg * 8]);
            const short8 b0h = *reinterpret_cast<const short8*>(pb0h + ks * 32);
            const short8 b0l = *reinterpret_cast<const short8*>(pb0l + ks * 32);
            const short8 b1h = *reinterpret_cast<const short8*>(pb1h + ks * 32);
            const short8 b1l = *reinterpret_cast<const short8*>(pb1l + ks * 32);
            acc00 = __builtin_amdgcn_mfma_f32_16x16x32_bf16(a0, b0h, acc00, 0, 0, 0);
            acc00 = __builtin_amdgcn_mfma_f32_16x16x32_bf16(a0, b0l, acc00, 0, 0, 0);
            acc10 = __builtin_amdgcn_mfma_f32_16x16x32_bf16(a1, b0h, acc10, 0, 0, 0);
            acc10 = __builtin_amdgcn_mfma_f32_16x16x32_bf16(a1, b0l, acc10, 0, 0, 0);
            acc01 = __builtin_amdgcn_mfma_f32_16x16x32_bf16(a0, b1h, acc01, 0, 0, 0);
            acc01 = __builtin_amdgcn_mfma_f32_16x16x32_bf16(a0, b1l, acc01, 0, 0, 0);
            acc11 = __builtin_amdgcn_mfma_f32_16x16x32_bf16(a1, b1h, acc11, 0, 0, 0);
            acc11 = __builtin_amdgcn_mfma_f32_16x16x32_bf16(a1, b1l, acc11, 0, 0, 0);
        }
    }
    // tanh -> h1 (f32 LDS). Garbage rows 20-31 stay bounded/NaN-contained (masked later).
#pragma unroll
    for (int r = 0; r < 4; ++r) {
        const int row = lg * 4 + r;
        h1S[row][n0]      = tanh_f(acc00[r]);
        h1S[row][n1]      = tanh_f(acc01[r]);
        h1S[16 + row][n0] = tanh_f(acc10[r]);
        h1S[16 + row][n1] = tanh_f(acc11[r]);
    }
    __syncthreads();

    // ---- layer 2: K = 128, 4 k-steps ----
    {
        const float bb0 = b2[n0], bb1 = b2[n1];
        acc00 = f32x4{bb0, bb0, bb0, bb0};  acc10 = acc00;
        acc01 = f32x4{bb1, bb1, bb1, bb1};  acc11 = acc01;
    }
    {
        const ushort* pb0h = w2Th + n0 * HID + lg * 8;
        const ushort* pb0l = w2Tl + n0 * HID + lg * 8;
        const ushort* pb1h = w2Th + n1 * HID + lg * 8;
        const ushort* pb1l = w2Tl + n1 * HID + lg * 8;
#pragma unroll
        for (int ks = 0; ks < 4; ++ks) {
            const float* pa0 = &h1S[lr][ks * 32 + lg * 8];
            const float* pa1 = &h1S[16 + lr][ks * 32 + lg * 8];
            const f32x4 u00 = *reinterpret_cast<const f32x4*>(pa0);
            const f32x4 u01 = *reinterpret_cast<const f32x4*>(pa0 + 4);
            const f32x4 u10 = *reinterpret_cast<const f32x4*>(pa1);
            const f32x4 u11 = *reinterpret_cast<const f32x4*>(pa1 + 4);
            short8 a0, a1;
#pragma unroll
            for (int j = 0; j < 4; ++j) {
                a0[j]     = (short)bfb(u00[j]);
                a0[4 + j] = (short)bfb(u01[j]);
                a1[j]     = (short)bfb(u10[j]);
                a1[4 + j] = (short)bfb(u11[j]);
            }
            const short8 b0h = *reinterpret_cast<const short8*>(pb0h + ks * 32);
            const short8 b0l = *reinterpret_cast<const short8*>(pb0l + ks * 32);
            const short8 b1h = *reinterpret_cast<const short8*>(pb1h + ks * 32);
            const short8 b1l = *reinterpret_cast<const short8*>(pb1l + ks * 32);
            acc00 = __builtin_amdgcn_mfma_f32_16x16x32_bf16(a0, b0h, acc00, 0, 0, 0);
            acc00 = __builtin_amdgcn_mfma_f32_16x16x32_bf16(a0, b0l, acc00, 0, 0, 0);
            acc10 = __builtin_amdgcn_mfma_f32_16x16x32_bf16(a1, b0h, acc10, 0, 0, 0);
            acc10 = __builtin_amdgcn_mfma_f32_16x16x32_bf16(a1, b0l, acc10, 0, 0, 0);
            acc01 = __builtin_amdgcn_mfma_f32_16x16x32_bf16(a0, b1h, acc01, 0, 0, 0);
            acc01 = __builtin_amdgcn_mfma_f32_16x16x32_bf16(a0, b1l, acc01, 0, 0, 0);
            acc11 = __builtin_amdgcn_mfma_f32_16x16x32_bf16(a1, b1h, acc11, 0, 0, 0);
            acc11 = __builtin_amdgcn_mfma_f32_16x16x32_bf16(a1, b1l, acc11, 0, 0, 0);
        }
    }

    // ---- epilogue: tanh + row<20-masked col-max + dot(w3) ----
    float m0 = -3.0e38f, m1 = -3.0e38f;    // col-max for nt0 / nt1
#pragma unroll
    for (int r = 0; r < 4; ++r) {          // m-tile 0: rows lg*4+r <= 15, all valid
        m0 = fmaxf(m0, tanh_f(acc00[r]));
        m1 = fmaxf(m1, tanh_f(acc01[r]));
    }
    if (lg == 0) {                          // m-tile 1: rows 16..19 valid only for lg==0
#pragma unroll
        for (int r = 0; r < 4; ++r) {
            m0 = fmaxf(m0, tanh_f(acc10[r]));
            m1 = fmaxf(m1, tanh_f(acc11[r]));
        }
    }
    // reduce over the 4 row-groups (lanes differing in bits 4-5)
    m0 = fmaxf(m0, __shfl_xor(m0, 16, 64));
    m0 = fmaxf(m0, __shfl_xor(m0, 32, 64));
    m1 = fmaxf(m1, __shfl_xor(m1, 16, 64));
    m1 = fmaxf(m1, __shfl_xor(m1, 32, 64));
    float vsum = m0 * w3[n0] + m1 * w3[n1];
#pragma unroll
    for (int off = 1; off < 16; off <<= 1) vsum += __shfl_xor(vsum, off, 64);
    if (ln == 0) red[wv] = vsum;
    __syncthreads();
    if (t == 0) out[pid] = red[0] + red[1] + red[2] + red[3] + b3[0];
}

} // namespace

extern "C" void kernel_launch(void* const* d_in, const int* in_sizes, int n_in,
                              void* d_out, int out_size, void* d_ws, size_t ws_size,
                              hipStream_t stream) {
    const float* pos = (const float*)d_in[0];
    const float* ori = (const float*)d_in[1];
    const float* w1  = (const float*)d_in[2];
    const float* b1  = (const float*)d_in[3];
    const float* w2  = (const float*)d_in[4];
    const float* b2  = (const float*)d_in[5];
    const float* w3  = (const float*)d_in[6];
    const float* b3  = (const float*)d_in[7];
    float* out = (float*)d_out;

    // ws layout: w1T hi/lo (128*96 each), w2T hi/lo (128*128 each) = 114688 B
    ushort* w1Th = (ushort*)d_ws;
    ushort* w1Tl = w1Th + 128 * 96;
    ushort* w2Th = w1Tl + 128 * 96;
    ushort* w2Tl = w2Th + 128 * 128;

    const int convElems = 128 * 96 + 128 * 128;
    conv_w_kernel<<<dim3((convElems + 255) / 256), dim3(256), 0, stream>>>(
        w1, w2, w1Th, w1Tl, w2Th, w2Tl);
    fused_kernel<<<dim3(B * N), dim3(256), 0, stream>>>(
        pos, ori, b1, b2, w3, b3, w1Th, w1Tl, w2Th, w2Tl, out);
}

// Round 8
// 274.363 us; speedup vs baseline: 2.3614x; 1.8379x over previous
//
#include <hip/hip_runtime.h>
#include <hip/hip_bf16.h>

namespace {

constexpr int B = 16;
constexpr int N = 1024;
constexpr int K = 20;
constexpr int HID = 128;
constexpr float BOX = 10.0f;

constexpr int KP1 = 96;                 // layer-1 K padded 78 -> 96 (3 k-steps of 32)
constexpr int FP = 104;                 // fS row pitch (bf16): 2-way banks (free)
constexpr int H1P = 136;                // h1 row pitch (bf16): 272B rows, 16B-aligned

constexpr uint HBASE = 1872;            // (117<<4): hist covers exp 117..132 (r2 in [2^-10, 32))

typedef __attribute__((ext_vector_type(8))) short short8;   // 8 bf16 = 4 VGPR
typedef __attribute__((ext_vector_type(4))) float f32x4;

__device__ __forceinline__ float tanh_f(float x) {
    float e = __expf(2.0f * x);
    return 1.0f - 2.0f / (e + 1.0f);
}

__device__ __forceinline__ ushort bfb(float x) {
    __hip_bfloat16 h = __float2bfloat16(x);
    return __builtin_bit_cast(ushort, h);
}

__device__ __forceinline__ uint r2bin(uint key) {
    int bv = (int)(key >> 19) - (int)HBASE;
    return (uint)min(255, max(0, bv));
}

// ---- weight preconversion: w1[78][128] -> w1T(hi/lo)[128][96] bf16 (transposed,
// K-padded); w2[128][128] -> w2T(hi/lo)[128][128]. hi+lo split => effectively f32
// weights through 2 MFMAs.
__global__ __launch_bounds__(256) void conv_w_kernel(
    const float* __restrict__ w1, const float* __restrict__ w2,
    ushort* __restrict__ w1Th, ushort* __restrict__ w1Tl,
    ushort* __restrict__ w2Th, ushort* __restrict__ w2Tl)
{
    const int idx = blockIdx.x * 256 + threadIdx.x;
    if (idx < 128 * KP1) {
        const int n = idx / KP1, k = idx - n * KP1;
        const float v = (k < 78) ? w1[k * HID + n] : 0.0f;
        const __hip_bfloat16 h = __float2bfloat16(v);
        w1Th[idx] = __builtin_bit_cast(ushort, h);
        w1Tl[idx] = bfb(v - __bfloat162float(h));
    } else if (idx < 128 * KP1 + 128 * 128) {
        const int i = idx - 128 * KP1;
        const int n = i >> 7, k = i & 127;
        const float v = w2[k * HID + n];
        const __hip_bfloat16 h = __float2bfloat16(v);
        w2Th[i] = __builtin_bit_cast(ushort, h);
        w2Tl[i] = bfb(v - __bfloat162float(h));
    }
}

// One block per particle: histogram-select 20-NN + features + MFMA MLP + maxpool.
__global__ __launch_bounds__(256) void fused_kernel(
    const float* __restrict__ pos, const float* __restrict__ ori,
    const float* __restrict__ b1, const float* __restrict__ b2,
    const float* __restrict__ w3, const float* __restrict__ b3,
    const ushort* __restrict__ w1Th, const ushort* __restrict__ w1Tl,
    const ushort* __restrict__ w2Th, const ushort* __restrict__ w2Tl,
    float* __restrict__ out)
{
    __shared__ __align__(16) __hip_bfloat16 fS[32][FP];  // rows 0-19 real, 20-31 don't-care
    __shared__ __align__(16) ushort h1S[32][H1P];        // bf16 h1; aliased below pre-MLP
    __shared__ int   nbrS[K];
    __shared__ float RpS[9];
    __shared__ float red[4];
    __shared__ int   TS;
    __shared__ uint  scntS;

    // hist/survivor buffers alias h1S (disjoint lifetime: selection vs layer-2)
    uint* const histS = (uint*)&h1S[0][0];                                   // 1024 B
    unsigned long long* const survS =
        (unsigned long long*)((char*)&h1S[0][0] + 1024);                     // 128*8 B

    const int pid = blockIdx.x;            // b*1024 + n
    const int b = pid >> 10;
    const int n = pid & (N - 1);
    const int t = threadIdx.x;
    const float* posb = pos + (size_t)b * N * 3;
    const float* orib = ori + (size_t)b * N * 9;

    if (t < 9) RpS[t] = orib[(size_t)n * 9 + t];   // visible after first barrier
    histS[t] = 0;                                   // t < 256 == bins
    if (t == 0) scntS = 0;

    const float xi = posb[n * 3 + 0];
    const float yi = posb[n * 3 + 1];
    const float zi = posb[n * 3 + 2];

    // ---- phase 1: all-pairs r2 (4 candidates/thread), min-image PBC ----
    float r2v[4];
    int   idv[4];
#pragma unroll
    for (int q = 0; q < 4; ++q) {
        const int j = t + q * 256;
        float dx = __fsub_rn(xi, posb[j * 3 + 0]);
        float dy = __fsub_rn(yi, posb[j * 3 + 1]);
        float dz = __fsub_rn(zi, posb[j * 3 + 2]);
        dx = __fsub_rn(dx, __fmul_rn(BOX, rintf(__fdiv_rn(dx, BOX))));
        dy = __fsub_rn(dy, __fmul_rn(BOX, rintf(__fdiv_rn(dy, BOX))));
        dz = __fsub_rn(dz, __fmul_rn(BOX, rintf(__fdiv_rn(dz, BOX))));
        float r2 = __fadd_rn(__fadd_rn(__fmul_rn(dx, dx), __fmul_rn(dy, dy)),
                             __fmul_rn(dz, dz));
        if (j == n) r2 = 1e9f;             // self-exclude (huge key -> bin 255)
        r2v[q] = r2;
        idv[q] = j;
    }
    __syncthreads();                        // hist zero + RpS visible

    // ---- phase 2: exact top-K via 256-bin histogram select ----
    // key = f32 bits (monotone for non-negative); bin monotone non-decreasing in key
#pragma unroll
    for (int q = 0; q < 4; ++q)
        atomicAdd(&histS[r2bin(__float_as_uint(r2v[q]))], 1u);
    __syncthreads();

    if (t < 64) {                           // wave 0: find first bin T with cum >= K
        const uint h0 = histS[4 * t + 0], h1v = histS[4 * t + 1];
        const uint h2v = histS[4 * t + 2], h3v = histS[4 * t + 3];
        const uint s = h0 + h1v + h2v + h3v;
        uint inc = s;
#pragma unroll
        for (int off = 1; off < 64; off <<= 1) {
            const uint v = __shfl_up(inc, off, 64);
            if (t >= off) inc += v;
        }
        const uint exc = inc - s;
        if (exc < (uint)K && inc >= (uint)K) {   // exactly one lane
            uint c = exc; int Tb = -1;
            c += h0; if (Tb < 0 && c >= (uint)K) Tb = 4 * t + 0;
            c += h1v; if (Tb < 0 && c >= (uint)K) Tb = 4 * t + 1;
            c += h2v; if (Tb < 0 && c >= (uint)K) Tb = 4 * t + 2;
            c += h3v; if (Tb < 0 && c >= (uint)K) Tb = 4 * t + 3;
            TS = Tb;
        }
    }
    __syncthreads();
    const uint T = (uint)TS;

    // compact survivors (bin <= T): packed (r2bits<<32)|idx == lax.top_k order
#pragma unroll
    for (int q = 0; q < 4; ++q) {
        const uint key = __float_as_uint(r2v[q]);
        if (r2bin(key) <= T) {
            const uint p = atomicAdd(&scntS, 1u);
            if (p < 128u)
                survS[p] = ((unsigned long long)key << 32) | (uint)idv[q];
        }
    }
    __syncthreads();

    const int S = min((int)scntS, 128);
    if (t < S) {                            // exact rank by counting (broadcast reads)
        const unsigned long long me = survS[t];
        int rank = 0;
        for (int j = 0; j < S; ++j) rank += (survS[j] < me) ? 1 : 0;
        if (rank < K) nbrS[rank] = (int)(me & 0xffffffffULL);
    }
    __syncthreads();

    // ---- phase 3: features, lane k < 20 builds its 78-vector (bf16 to LDS) ----
    if (t < K) {
        const int j = nbrS[t];
        float Rp[9], Rn[9];
#pragma unroll
        for (int q = 0; q < 9; ++q) Rp[q] = RpS[q];
#pragma unroll
        for (int q = 0; q < 9; ++q) Rn[q] = orib[(size_t)j * 9 + q];

        float dx = __fsub_rn(xi, posb[j * 3 + 0]);
        float dy = __fsub_rn(yi, posb[j * 3 + 1]);
        float dz = __fsub_rn(zi, posb[j * 3 + 2]);
        dx = __fsub_rn(dx, __fmul_rn(BOX, rintf(__fdiv_rn(dx, BOX))));
        dy = __fsub_rn(dy, __fmul_rn(BOX, rintf(__fdiv_rn(dy, BOX))));
        dz = __fsub_rn(dz, __fmul_rn(BOX, rintf(__fdiv_rn(dz, BOX))));
        const float r2 = __fadd_rn(__fadd_rn(__fmul_rn(dx, dx), __fmul_rn(dy, dy)),
                                   __fmul_rn(dz, dz));
        const float r = sqrtf(r2);
        const float invr = 1.0f / r;
        const float ux = dx / r, uy = dy / r, uz = dz / r;

        __hip_bfloat16* f = (__hip_bfloat16*)fS[t];
        f[0] = __float2bfloat16(r);
        f[1] = __float2bfloat16(invr);
        f[2] = __float2bfloat16(ux);
        f[3] = __float2bfloat16(uy);
        f[4] = __float2bfloat16(uz);

        float diag[3];
#pragma unroll
        for (int i = 0; i < 3; ++i) {
#pragma unroll
            for (int l = 0; l < 3; ++l) {
                float s = 0.0f, en2 = 0.0f;
#pragma unroll
                for (int m = 0; m < 3; ++m) {
                    const float e = Rp[i * 3 + m] * Rn[l * 3 + m];
                    f[14 + i * 9 + l * 3 + m] = __float2bfloat16(e);
                    en2 += e * e;
                    s += e;
                }
                f[5 + i * 3 + l] = __float2bfloat16(s);
                f[41 + i * 3 + l] = __float2bfloat16(sqrtf(en2));
                float rr = 0.0f;
#pragma unroll
                for (int m = 0; m < 3; ++m) rr += Rp[m * 3 + i] * Rn[m * 3 + l];
                f[62 + i * 3 + l] = __float2bfloat16(rr);
                if (i == l) diag[i] = rr;
            }
        }
#pragma unroll
        for (int i = 0; i < 3; ++i) {
            const float ax = Rp[i * 3 + 0], ay = Rp[i * 3 + 1], az = Rp[i * 3 + 2];
            const float bx = Rn[i * 3 + 0], by = Rn[i * 3 + 1], bz = Rn[i * 3 + 2];
            const float cx = ay * bz - az * by;
            const float cy = az * bx - ax * bz;
            const float cz = ax * by - ay * bx;
            f[50 + i * 3 + 0] = __float2bfloat16(cx);
            f[50 + i * 3 + 1] = __float2bfloat16(cy);
            f[50 + i * 3 + 2] = __float2bfloat16(cz);
            f[59 + i] = __float2bfloat16(sqrtf(cx * cx + cy * cy + cz * cz));
            const float dp = ux * ax + uy * ay + uz * az;
            f[71 + i] = __float2bfloat16(__expf(-dp * dp));
            const float dn = ux * bx + uy * by + uz * bz;
            f[74 + i] = __float2bfloat16(__expf(-dn * dn));
        }
        const float tr = diag[0] + diag[1] + diag[2];
        float ca = (tr - 1.0f) * 0.5f;
        ca = fminf(fmaxf(ca, -1.0f + 1e-6f), 1.0f - 1e-6f);
        f[77] = __float2bfloat16(acosf(ca));
#pragma unroll
        for (int i = 78; i < KP1; ++i) f[i] = __float2bfloat16(0.0f);  // K-pad
    }
    __syncthreads();

    // ---- MFMA MLP: wave wv owns output cols [32wv, 32wv+32) ----
    const int wv = t >> 6, ln = t & 63;
    const int lr = ln & 15, lg = ln >> 4;
    const int n0 = wv * 32 + lr, n1 = n0 + 16;

    f32x4 acc00, acc01, acc10, acc11;       // [mtile][ntile]
    {
        const float bb0 = b1[n0], bb1 = b1[n1];
        acc00 = f32x4{bb0, bb0, bb0, bb0};  acc10 = acc00;
        acc01 = f32x4{bb1, bb1, bb1, bb1};  acc11 = acc01;
    }
    {
        const ushort* pb0h = w1Th + n0 * KP1 + lg * 8;
        const ushort* pb0l = w1Tl + n0 * KP1 + lg * 8;
        const ushort* pb1h = w1Th + n1 * KP1 + lg * 8;
        const ushort* pb1l = w1Tl + n1 * KP1 + lg * 8;
#pragma unroll
        for (int ks = 0; ks < 3; ++ks) {
            const short8 a0 = *reinterpret_cast<const short8*>(&fS[lr][ks * 32 + lg * 8]);
            const short8 a1 = *reinterpret_cast<const short8*>(&fS[16 + lr][ks * 32 + lg * 8]);
            const short8 b0h = *reinterpret_cast<const short8*>(pb0h + ks * 32);
            const short8 b0l = *reinterpret_cast<const short8*>(pb0l + ks * 32);
            const short8 b1h = *reinterpret_cast<const short8*>(pb1h + ks * 32);
            const short8 b1l = *reinterpret_cast<const short8*>(pb1l + ks * 32);
            acc00 = __builtin_amdgcn_mfma_f32_16x16x32_bf16(a0, b0h, acc00, 0, 0, 0);
            acc00 = __builtin_amdgcn_mfma_f32_16x16x32_bf16(a0, b0l, acc00, 0, 0, 0);
            acc10 = __builtin_amdgcn_mfma_f32_16x16x32_bf16(a1, b0h, acc10, 0, 0, 0);
            acc10 = __builtin_amdgcn_mfma_f32_16x16x32_bf16(a1, b0l, acc10, 0, 0, 0);
            acc01 = __builtin_amdgcn_mfma_f32_16x16x32_bf16(a0, b1h, acc01, 0, 0, 0);
            acc01 = __builtin_amdgcn_mfma_f32_16x16x32_bf16(a0, b1l, acc01, 0, 0, 0);
            acc11 = __builtin_amdgcn_mfma_f32_16x16x32_bf16(a1, b1h, acc11, 0, 0, 0);
            acc11 = __builtin_amdgcn_mfma_f32_16x16x32_bf16(a1, b1l, acc11, 0, 0, 0);
        }
    }
    __syncthreads();                        // selection aliases (histS/survS) done; h1S safe
    // tanh -> h1 bf16 (identical rounding to the old repack path)
#pragma unroll
    for (int r = 0; r < 4; ++r) {
        const int row = lg * 4 + r;
        h1S[row][n0]      = bfb(tanh_f(acc00[r]));
        h1S[row][n1]      = bfb(tanh_f(acc01[r]));
        h1S[16 + row][n0] = bfb(tanh_f(acc10[r]));
        h1S[16 + row][n1] = bfb(tanh_f(acc11[r]));
    }
    __syncthreads();

    // ---- layer 2: K = 128, 4 k-steps, A direct from bf16 LDS ----
    {
        const float bb0 = b2[n0], bb1 = b2[n1];
        acc00 = f32x4{bb0, bb0, bb0, bb0};  acc10 = acc00;
        acc01 = f32x4{bb1, bb1, bb1, bb1};  acc11 = acc01;
    }
    {
        const ushort* pb0h = w2Th + n0 * HID + lg * 8;
        const ushort* pb0l = w2Tl + n0 * HID + lg * 8;
        const ushort* pb1h = w2Th + n1 * HID + lg * 8;
        const ushort* pb1l = w2Tl + n1 * HID + lg * 8;
#pragma unroll
        for (int ks = 0; ks < 4; ++ks) {
            const short8 a0 = *reinterpret_cast<const short8*>(&h1S[lr][ks * 32 + lg * 8]);
            const short8 a1 = *reinterpret_cast<const short8*>(&h1S[16 + lr][ks * 32 + lg * 8]);
            const short8 b0h = *reinterpret_cast<const short8*>(pb0h + ks * 32);
            const short8 b0l = *reinterpret_cast<const short8*>(pb0l + ks * 32);
            const short8 b1h = *reinterpret_cast<const short8*>(pb1h + ks * 32);
            const short8 b1l = *reinterpret_cast<const short8*>(pb1l + ks * 32);
            acc00 = __builtin_amdgcn_mfma_f32_16x16x32_bf16(a0, b0h, acc00, 0, 0, 0);
            acc00 = __builtin_amdgcn_mfma_f32_16x16x32_bf16(a0, b0l, acc00, 0, 0, 0);
            acc10 = __builtin_amdgcn_mfma_f32_16x16x32_bf16(a1, b0h, acc10, 0, 0, 0);
            acc10 = __builtin_amdgcn_mfma_f32_16x16x32_bf16(a1, b0l, acc10, 0, 0, 0);
            acc01 = __builtin_amdgcn_mfma_f32_16x16x32_bf16(a0, b1h, acc01, 0, 0, 0);
            acc01 = __builtin_amdgcn_mfma_f32_16x16x32_bf16(a0, b1l, acc01, 0, 0, 0);
            acc11 = __builtin_amdgcn_mfma_f32_16x16x32_bf16(a1, b1h, acc11, 0, 0, 0);
            acc11 = __builtin_amdgcn_mfma_f32_16x16x32_bf16(a1, b1l, acc11, 0, 0, 0);
        }
    }

    // ---- epilogue: tanh + row<20-masked col-max + dot(w3) ----
    float m0 = -3.0e38f, m1 = -3.0e38f;
#pragma unroll
    for (int r = 0; r < 4; ++r) {          // m-tile 0 rows (0..15): all valid
        m0 = fmaxf(m0, tanh_f(acc00[r]));
        m1 = fmaxf(m1, tanh_f(acc01[r]));
    }
    if (lg == 0) {                          // m-tile 1: rows 16..19 valid only for lg==0
#pragma unroll
        for (int r = 0; r < 4; ++r) {
            m0 = fmaxf(m0, tanh_f(acc10[r]));
            m1 = fmaxf(m1, tanh_f(acc11[r]));
        }
    }
    m0 = fmaxf(m0, __shfl_xor(m0, 16, 64));
    m0 = fmaxf(m0, __shfl_xor(m0, 32, 64));
    m1 = fmaxf(m1, __shfl_xor(m1, 16, 64));
    m1 = fmaxf(m1, __shfl_xor(m1, 32, 64));
    float vsum = m0 * w3[n0] + m1 * w3[n1];
#pragma unroll
    for (int off = 1; off < 16; off <<= 1) vsum += __shfl_xor(vsum, off, 64);
    if (ln == 0) red[wv] = vsum;
    __syncthreads();
    if (t == 0) out[pid] = red[0] + red[1] + red[2] + red[3] + b3[0];
}

} // namespace

extern "C" void kernel_launch(void* const* d_in, const int* in_sizes, int n_in,
                              void* d_out, int out_size, void* d_ws, size_t ws_size,
                              hipStream_t stream) {
    const float* pos = (const float*)d_in[0];
    const float* ori = (const float*)d_in[1];
    const float* w1  = (const float*)d_in[2];
    const float* b1  = (const float*)d_in[3];
    const float* w2  = (const float*)d_in[4];
    const float* b2  = (const float*)d_in[5];
    const float* w3  = (const float*)d_in[6];
    const float* b3  = (const float*)d_in[7];
    float* out = (float*)d_out;

    // ws layout: w1T hi/lo (128*96 each), w2T hi/lo (128*128 each) = 114688 B
    ushort* w1Th = (ushort*)d_ws;
    ushort* w1Tl = w1Th + 128 * 96;
    ushort* w2Th = w1Tl + 128 * 96;
    ushort* w2Tl = w2Th + 128 * 128;

    const int convElems = 128 * 96 + 128 * 128;
    conv_w_kernel<<<dim3((convElems + 255) / 256), dim3(256), 0, stream>>>(
        w1, w2, w1Th, w1Tl, w2Th, w2Tl);
    fused_kernel<<<dim3(B * N), dim3(256), 0, stream>>>(
        pos, ori, b1, b2, w3, b3, w1Th, w1Tl, w2Th, w2Tl, out);
}

// Round 10
// 170.449 us; speedup vs baseline: 3.8010x; 1.6096x over previous
//
#include <hip/hip_runtime.h>
#include <hip/hip_bf16.h>

namespace {

constexpr int B = 16;
constexpr int N = 1024;
constexpr int K = 20;
constexpr int HID = 128;
constexpr float BOX = 10.0f;

constexpr int PPB = 4;                  // particles per block
constexpr int MROWS = PPB * K;          // 80 = 5 m-tiles exactly, no padding
constexpr int MT = 5;                   // m-tiles of 16
constexpr int KP1 = 96;                 // layer-1 K padded 78 -> 96
constexpr int FP = 104;                 // fS row pitch (bf16)
constexpr int H1P = 136;                // h1 row pitch (bf16), 272B rows
constexpr int SURVCAP = 96;             // survivor list cap per particle

constexpr uint HBASE = 1872;            // (117<<4): bins cover r2 in [2^-10, 64)

typedef __attribute__((ext_vector_type(8))) short short8;   // 8 bf16 = 4 VGPR
typedef __attribute__((ext_vector_type(4))) float f32x4;

__device__ __forceinline__ float tanh_f(float x) {
    float e = __expf(2.0f * x);
    return 1.0f - 2.0f / (e + 1.0f);
}

__device__ __forceinline__ ushort bfb(float x) {
    __hip_bfloat16 h = __float2bfloat16(x);
    return __builtin_bit_cast(ushort, h);
}

__device__ __forceinline__ uint r2bin(uint key) {
    int bv = (int)(key >> 19) - (int)HBASE;
    return (uint)min(255, max(0, bv));
}

// Exact min-image for |d| < 10: rint(fl(d/10)) == (d>5) - (d<-5).
// Proof: 5.0/10 = 0.5 exact; div is monotone; ties-to-even sends 0.5 -> 0;
// first f32 above 5.0 maps above 0.5. d -/+ 10 is Sterbenz-exact in (5,10).
__device__ __forceinline__ float pbc(float d) {
    const float hi = __fsub_rn(d, BOX);
    const float lo = __fadd_rn(d, BOX);
    return d > 5.0f ? hi : (d < -5.0f ? lo : d);
}

// ---- weight preconversion: transposed, K-padded, hi/lo bf16 split (== f32 weights
// through 2 MFMAs).
__global__ __launch_bounds__(256) void conv_w_kernel(
    const float* __restrict__ w1, const float* __restrict__ w2,
    ushort* __restrict__ w1Th, ushort* __restrict__ w1Tl,
    ushort* __restrict__ w2Th, ushort* __restrict__ w2Tl)
{
    const int idx = blockIdx.x * 256 + threadIdx.x;
    if (idx < 128 * KP1) {
        const int n = idx / KP1, k = idx - n * KP1;
        const float v = (k < 78) ? w1[k * HID + n] : 0.0f;
        const __hip_bfloat16 h = __float2bfloat16(v);
        w1Th[idx] = __builtin_bit_cast(ushort, h);
        w1Tl[idx] = bfb(v - __bfloat162float(h));
    } else if (idx < 128 * KP1 + 128 * 128) {
        const int i = idx - 128 * KP1;
        const int n = i >> 7, k = i & 127;
        const float v = w2[k * HID + n];
        const __hip_bfloat16 h = __float2bfloat16(v);
        w2Th[i] = __builtin_bit_cast(ushort, h);
        w2Tl[i] = bfb(v - __bfloat162float(h));
    }
}

// One block = 4 particles: histogram-select 20-NN x4 + features (80 rows) +
// MFMA MLP (M=80, zero pad waste) + in-register masked maxpool + energy.
__global__ __launch_bounds__(256, 4) void fused_kernel(
    const float* __restrict__ pos, const float* __restrict__ ori,
    const float* __restrict__ b1, const float* __restrict__ b2,
    const float* __restrict__ w3, const float* __restrict__ b3,
    const ushort* __restrict__ w1Th, const ushort* __restrict__ w1Tl,
    const ushort* __restrict__ w2Th, const ushort* __restrict__ w2Tl,
    float* __restrict__ out)
{
    __shared__ __align__(16) __hip_bfloat16 fS[MROWS][FP];
    __shared__ __align__(16) ushort h1S[MROWS][H1P];
    __shared__ int   nbrS[PPB][K];
    __shared__ float RpS[PPB][9];
    __shared__ float red[4][PPB];
    __shared__ int   TS[PPB];
    __shared__ uint  scntS[PPB];

    // selection scratch aliases h1S (disjoint lifetime): hist 4KB + surv 3KB
    uint* const histS = (uint*)&h1S[0][0];                                  // [4][256]
    unsigned long long* const survS =
        (unsigned long long*)((char*)&h1S[0][0] + 4096);                    // [4][96]

    const int pid0 = blockIdx.x * PPB;
    const int b  = pid0 >> 10;
    const int nb = pid0 & (N - 1);          // 4 | 1024 -> all 4 particles same batch
    const int t  = threadIdx.x;
    const float* posb = pos + (size_t)b * N * 3;
    const float* orib = ori + (size_t)b * N * 9;

#pragma unroll
    for (int i = 0; i < 4; ++i) histS[i * 256 + t] = 0;
    if (t < PPB) scntS[t] = 0;
    if (t < PPB * 9) RpS[t / 9][t % 9] = orib[(size_t)(nb + t / 9) * 9 + (t % 9)];

    float cx[PPB], cy[PPB], cz[PPB];
#pragma unroll
    for (int p = 0; p < PPB; ++p) {
        cx[p] = posb[(nb + p) * 3 + 0];
        cy[p] = posb[(nb + p) * 3 + 1];
        cz[p] = posb[(nb + p) * 3 + 2];
    }

    // ---- phase 1: r2 for 4 particles x 4 candidates (pos loads shared) ----
    float r2v[PPB][4];
#pragma unroll
    for (int q = 0; q < 4; ++q) {
        const int j = t + q * 256;
        const float px = posb[j * 3 + 0];
        const float py = posb[j * 3 + 1];
        const float pz = posb[j * 3 + 2];
#pragma unroll
        for (int p = 0; p < PPB; ++p) {
            const float dx = pbc(__fsub_rn(cx[p], px));
            const float dy = pbc(__fsub_rn(cy[p], py));
            const float dz = pbc(__fsub_rn(cz[p], pz));
            float r2 = __fadd_rn(__fadd_rn(__fmul_rn(dx, dx), __fmul_rn(dy, dy)),
                                 __fmul_rn(dz, dz));
            if (j == nb + p) r2 = 1e9f;
            r2v[p][q] = r2;
        }
    }
    __syncthreads();                        // hist zero + RpS visible

    // ---- phase 2: 4 histograms ----
#pragma unroll
    for (int p = 0; p < PPB; ++p)
#pragma unroll
        for (int q = 0; q < 4; ++q)
            atomicAdd(&histS[p * 256 + r2bin(__float_as_uint(r2v[p][q]))], 1u);
    __syncthreads();

    {   // wave p scans particle p's histogram for the rank-K bin
        const int p = t >> 6, lane = t & 63;
        const uint* hp = histS + p * 256;
        const uint h0 = hp[4 * lane + 0], h1v = hp[4 * lane + 1];
        const uint h2v = hp[4 * lane + 2], h3v = hp[4 * lane + 3];
        const uint s = h0 + h1v + h2v + h3v;
        uint inc = s;
#pragma unroll
        for (int off = 1; off < 64; off <<= 1) {
            const uint v = __shfl_up(inc, off, 64);
            if (lane >= off) inc += v;
        }
        const uint exc = inc - s;
        if (exc < (uint)K && inc >= (uint)K) {
            uint c = exc; int Tb = -1;
            c += h0;  if (Tb < 0 && c >= (uint)K) Tb = 4 * lane + 0;
            c += h1v; if (Tb < 0 && c >= (uint)K) Tb = 4 * lane + 1;
            c += h2v; if (Tb < 0 && c >= (uint)K) Tb = 4 * lane + 2;
            c += h3v; if (Tb < 0 && c >= (uint)K) Tb = 4 * lane + 3;
            TS[p] = Tb;
        }
    }
    __syncthreads();

    // ---- compact survivors per particle ----
#pragma unroll
    for (int p = 0; p < PPB; ++p) {
        const uint T = (uint)TS[p];
#pragma unroll
        for (int q = 0; q < 4; ++q) {
            const uint key = __float_as_uint(r2v[p][q]);
            if (r2bin(key) <= T) {
                const uint pp = atomicAdd(&scntS[p], 1u);
                if (pp < (uint)SURVCAP)
                    survS[p * SURVCAP + pp] =
                        ((unsigned long long)key << 32) | (uint)(t + q * 256);
            }
        }
    }
    __syncthreads();

    {   // exact rank by counting; order matches lax.top_k (r2 asc, idx asc)
        const int p = t >> 6;
        const int S = min((int)scntS[p], SURVCAP);
        const unsigned long long* sp = survS + p * SURVCAP;
#pragma unroll
        for (int half = 0; half < 2; ++half) {
            const int s = (t & 63) + half * 64;
            if (s < S) {
                const unsigned long long me = sp[s];
                int rank = 0;
                for (int jj = 0; jj < S; ++jj) rank += (sp[jj] < me) ? 1 : 0;
                if (rank < K) nbrS[p][rank] = (int)(me & 0xffffffffULL);
            }
        }
    }
    __syncthreads();

    // ---- phase 3: features, 80 lanes (p = t/20, k = t%20) -> fS[p*20+k] ----
    if (t < PPB * K) {
        const int p = t / K, k = t - p * K;
        const int j = nbrS[p][k];
        float Rp[9], Rn[9];
#pragma unroll
        for (int q = 0; q < 9; ++q) Rp[q] = RpS[p][q];
#pragma unroll
        for (int q = 0; q < 9; ++q) Rn[q] = orib[(size_t)j * 9 + q];

        const float cxp = posb[(nb + p) * 3 + 0];
        const float cyp = posb[(nb + p) * 3 + 1];
        const float czp = posb[(nb + p) * 3 + 2];
        const float dx = pbc(__fsub_rn(cxp, posb[j * 3 + 0]));
        const float dy = pbc(__fsub_rn(cyp, posb[j * 3 + 1]));
        const float dz = pbc(__fsub_rn(czp, posb[j * 3 + 2]));
        const float r2 = __fadd_rn(__fadd_rn(__fmul_rn(dx, dx), __fmul_rn(dy, dy)),
                                   __fmul_rn(dz, dz));
        const float r = sqrtf(r2);
        const float invr = 1.0f / r;
        const float ux = dx * invr, uy = dy * invr, uz = dz * invr;

        __hip_bfloat16* f = fS[p * K + k];
        f[0] = __float2bfloat16(r);
        f[1] = __float2bfloat16(invr);
        f[2] = __float2bfloat16(ux);
        f[3] = __float2bfloat16(uy);
        f[4] = __float2bfloat16(uz);

        float diag[3];
#pragma unroll
        for (int i = 0; i < 3; ++i) {
#pragma unroll
            for (int l = 0; l < 3; ++l) {
                float s = 0.0f, en2 = 0.0f;
#pragma unroll
                for (int m = 0; m < 3; ++m) {
                    const float e = Rp[i * 3 + m] * Rn[l * 3 + m];
                    f[14 + i * 9 + l * 3 + m] = __float2bfloat16(e);
                    en2 += e * e;
                    s += e;
                }
                f[5 + i * 3 + l] = __float2bfloat16(s);
                f[41 + i * 3 + l] = __float2bfloat16(sqrtf(en2));
                float rr = 0.0f;
#pragma unroll
                for (int m = 0; m < 3; ++m) rr += Rp[m * 3 + i] * Rn[m * 3 + l];
                f[62 + i * 3 + l] = __float2bfloat16(rr);
                if (i == l) diag[i] = rr;
            }
        }
#pragma unroll
        for (int i = 0; i < 3; ++i) {
            const float ax = Rp[i * 3 + 0], ay = Rp[i * 3 + 1], az = Rp[i * 3 + 2];
            const float bx = Rn[i * 3 + 0], by = Rn[i * 3 + 1], bz = Rn[i * 3 + 2];
            const float ccx = ay * bz - az * by;
            const float ccy = az * bx - ax * bz;
            const float ccz = ax * by - ay * bx;
            f[50 + i * 3 + 0] = __float2bfloat16(ccx);
            f[50 + i * 3 + 1] = __float2bfloat16(ccy);
            f[50 + i * 3 + 2] = __float2bfloat16(ccz);
            f[59 + i] = __float2bfloat16(sqrtf(ccx * ccx + ccy * ccy + ccz * ccz));
            const float dp = ux * ax + uy * ay + uz * az;
            f[71 + i] = __float2bfloat16(__expf(-dp * dp));
            const float dn = ux * bx + uy * by + uz * bz;
            f[74 + i] = __float2bfloat16(__expf(-dn * dn));
        }
        const float tr = diag[0] + diag[1] + diag[2];
        float ca = (tr - 1.0f) * 0.5f;
        ca = fminf(fmaxf(ca, -1.0f + 1e-6f), 1.0f - 1e-6f);
        f[77] = __float2bfloat16(acosf(ca));
#pragma unroll
        for (int i = 78; i < KP1; ++i) f[i] = __float2bfloat16(0.0f);
    }
    __syncthreads();

    // ---- MFMA MLP: wave wv owns cols [32wv,32wv+32); M = 80 (5 m-tiles) ----
    const int wv = t >> 6, ln = t & 63;
    const int lr = ln & 15, lg = ln >> 4;
    const int n0 = wv * 32 + lr, n1 = n0 + 16;

    f32x4 acc[MT][2];
    {
        const float bb0 = b1[n0], bb1 = b1[n1];
#pragma unroll
        for (int mt = 0; mt < MT; ++mt) {
            acc[mt][0] = f32x4{bb0, bb0, bb0, bb0};
            acc[mt][1] = f32x4{bb1, bb1, bb1, bb1};
        }
    }
    {
        const ushort* pb0h = w1Th + n0 * KP1 + lg * 8;
        const ushort* pb0l = w1Tl + n0 * KP1 + lg * 8;
        const ushort* pb1h = w1Th + n1 * KP1 + lg * 8;
        const ushort* pb1l = w1Tl + n1 * KP1 + lg * 8;
#pragma unroll
        for (int ks = 0; ks < 3; ++ks) {
            const short8 b0h = *reinterpret_cast<const short8*>(pb0h + ks * 32);
            const short8 b0l = *reinterpret_cast<const short8*>(pb0l + ks * 32);
            const short8 b1h = *reinterpret_cast<const short8*>(pb1h + ks * 32);
            const short8 b1l = *reinterpret_cast<const short8*>(pb1l + ks * 32);
#pragma unroll
            for (int mt = 0; mt < MT; ++mt) {
                const short8 a = *reinterpret_cast<const short8*>(
                    &fS[16 * mt + lr][ks * 32 + lg * 8]);
                acc[mt][0] = __builtin_amdgcn_mfma_f32_16x16x32_bf16(a, b0h, acc[mt][0], 0, 0, 0);
                acc[mt][0] = __builtin_amdgcn_mfma_f32_16x16x32_bf16(a, b0l, acc[mt][0], 0, 0, 0);
                acc[mt][1] = __builtin_amdgcn_mfma_f32_16x16x32_bf16(a, b1h, acc[mt][1], 0, 0, 0);
                acc[mt][1] = __builtin_amdgcn_mfma_f32_16x16x32_bf16(a, b1l, acc[mt][1], 0, 0, 0);
            }
        }
    }
    // tanh -> h1 bf16 (selection aliases long dead; each wave writes its own cols)
#pragma unroll
    for (int mt = 0; mt < MT; ++mt)
#pragma unroll
        for (int r = 0; r < 4; ++r) {
            h1S[16 * mt + 4 * lg + r][n0] = bfb(tanh_f(acc[mt][0][r]));
            h1S[16 * mt + 4 * lg + r][n1] = bfb(tanh_f(acc[mt][1][r]));
        }
    __syncthreads();

    // ---- layer 2: K = 128 ----
    {
        const float bb0 = b2[n0], bb1 = b2[n1];
#pragma unroll
        for (int mt = 0; mt < MT; ++mt) {
            acc[mt][0] = f32x4{bb0, bb0, bb0, bb0};
            acc[mt][1] = f32x4{bb1, bb1, bb1, bb1};
        }
    }
    {
        const ushort* pb0h = w2Th + n0 * HID + lg * 8;
        const ushort* pb0l = w2Tl + n0 * HID + lg * 8;
        const ushort* pb1h = w2Th + n1 * HID + lg * 8;
        const ushort* pb1l = w2Tl + n1 * HID + lg * 8;
#pragma unroll
        for (int ks = 0; ks < 4; ++ks) {
            const short8 b0h = *reinterpret_cast<const short8*>(pb0h + ks * 32);
            const short8 b0l = *reinterpret_cast<const short8*>(pb0l + ks * 32);
            const short8 b1h = *reinterpret_cast<const short8*>(pb1h + ks * 32);
            const short8 b1l = *reinterpret_cast<const short8*>(pb1l + ks * 32);
#pragma unroll
            for (int mt = 0; mt < MT; ++mt) {
                const short8 a = *reinterpret_cast<const short8*>(
                    &h1S[16 * mt + lr][ks * 32 + lg * 8]);
                acc[mt][0] = __builtin_amdgcn_mfma_f32_16x16x32_bf16(a, b0h, acc[mt][0], 0, 0, 0);
                acc[mt][0] = __builtin_amdgcn_mfma_f32_16x16x32_bf16(a, b0l, acc[mt][0], 0, 0, 0);
                acc[mt][1] = __builtin_amdgcn_mfma_f32_16x16x32_bf16(a, b1h, acc[mt][1], 0, 0, 0);
                acc[mt][1] = __builtin_amdgcn_mfma_f32_16x16x32_bf16(a, b1l, acc[mt][1], 0, 0, 0);
            }
        }
    }

    // ---- in-register epilogue: tanh, masked per-particle maxpool, dot w3 ----
    // C-row = 16mt + 4lg + r; 4-row group G = 4mt+lg; particle p <=> G in [5p,5p+5)
#pragma unroll
    for (int mt = 0; mt < MT; ++mt)
#pragma unroll
        for (int nt = 0; nt < 2; ++nt)
#pragma unroll
            for (int r = 0; r < 4; ++r) acc[mt][nt][r] = tanh_f(acc[mt][nt][r]);

    const float w3n0 = w3[n0], w3n1 = w3[n1];
#pragma unroll
    for (int p = 0; p < PPB; ++p) {
        float m0 = -3.0e38f, m1 = -3.0e38f;
#pragma unroll
        for (int mt = 0; mt < MT; ++mt) {
            const bool in = (uint)(4 * mt + lg - 5 * p) < 5u;
#pragma unroll
            for (int r = 0; r < 4; ++r) {
                m0 = fmaxf(m0, in ? acc[mt][0][r] : -3.0e38f);
                m1 = fmaxf(m1, in ? acc[mt][1][r] : -3.0e38f);
            }
        }
        m0 = fmaxf(m0, __shfl_xor(m0, 16, 64));
        m0 = fmaxf(m0, __shfl_xor(m0, 32, 64));
        m1 = fmaxf(m1, __shfl_xor(m1, 16, 64));
        m1 = fmaxf(m1, __shfl_xor(m1, 32, 64));
        float v = m0 * w3n0 + m1 * w3n1;
#pragma unroll
        for (int off = 1; off < 16; off <<= 1) v += __shfl_xor(v, off, 64);
        if (ln == 0) red[wv][p] = v;
    }
    __syncthreads();
    if (t < PPB) out[pid0 + t] = red[0][t] + red[1][t] + red[2][t] + red[3][t] + b3[0];
}

} // namespace

extern "C" void kernel_launch(void* const* d_in, const int* in_sizes, int n_in,
                              void* d_out, int out_size, void* d_ws, size_t ws_size,
                              hipStream_t stream) {
    const float* pos = (const float*)d_in[0];
    const float* ori = (const float*)d_in[1];
    const float* w1  = (const float*)d_in[2];
    const float* b1  = (const float*)d_in[3];
    const float* w2  = (const float*)d_in[4];
    const float* b2  = (const float*)d_in[5];
    const float* w3  = (const float*)d_in[6];
    const float* b3  = (const float*)d_in[7];
    float* out = (float*)d_out;

    // ws layout: w1T hi/lo (128*96 each), w2T hi/lo (128*128 each) = 114688 B
    ushort* w1Th = (ushort*)d_ws;
    ushort* w1Tl = w1Th + 128 * 96;
    ushort* w2Th = w1Tl + 128 * 96;
    ushort* w2Tl = w2Th + 128 * 128;

    const int convElems = 128 * 96 + 128 * 128;
    conv_w_kernel<<<dim3((convElems + 255) / 256), dim3(256), 0, stream>>>(
        w1, w2, w1Th, w1Tl, w2Th, w2Tl);
    fused_kernel<<<dim3(B * N / PPB), dim3(256), 0, stream>>>(
        pos, ori, b1, b2, w3, b3, w1Th, w1Tl, w2Th, w2Tl, out);
}

// Round 11
// 167.894 us; speedup vs baseline: 3.8588x; 1.0152x over previous
//
#include <hip/hip_runtime.h>
#include <hip/hip_bf16.h>

namespace {

constexpr int B = 16;
constexpr int N = 1024;
constexpr int K = 20;
constexpr int HID = 128;
constexpr float BOX = 10.0f;

constexpr int PPB = 4;                  // particles per block
constexpr int MROWS = PPB * K;          // 80 = 5 m-tiles exactly
constexpr int MT = 5;
constexpr int KP1 = 96;                 // layer-1 K padded 78 -> 96
constexpr int FP = 104;                 // fS row pitch (bf16)
constexpr int H1P = 136;                // h1 row pitch (bf16)
constexpr int SURVCAP = 96;

constexpr uint HBASE = 1872;            // bins cover r2 in [2^-10, 64)

constexpr int GRID_SEL  = B * N / PPB;              // 4096
constexpr int CONV_ELEMS = 128 * KP1 + 128 * 128;   // 28672
constexpr int GRID_CONV = (CONV_ELEMS + 255) / 256; // 112

typedef __attribute__((ext_vector_type(8))) short short8;
typedef __attribute__((ext_vector_type(4))) float f32x4;

__device__ __forceinline__ float tanh_f(float x) {
    float e = __expf(2.0f * x);
    return 1.0f - 2.0f / (e + 1.0f);
}

__device__ __forceinline__ ushort bfb(float x) {
    __hip_bfloat16 h = __float2bfloat16(x);
    return __builtin_bit_cast(ushort, h);
}

__device__ __forceinline__ uint r2bin(uint key) {
    int bv = (int)(key >> 19) - (int)HBASE;
    return (uint)min(255, max(0, bv));
}

// Exact min-image for |d| < 10: rint(fl(d/10)) == (d>5) - (d<-5).  (Sterbenz)
__device__ __forceinline__ float pbc(float d) {
    const float hi = __fsub_rn(d, BOX);
    const float lo = __fadd_rn(d, BOX);
    return d > 5.0f ? hi : (d < -5.0f ? lo : d);
}

// ---- kernel 1: 20-NN selection (lean LDS, high occupancy) + weight conversion
// in trailing blocks. nbr written as ushort (idx < 1024).
__global__ __launch_bounds__(256, 8) void select_kernel(
    const float* __restrict__ pos,
    const float* __restrict__ w1, const float* __restrict__ w2,
    ushort* __restrict__ w1Th, ushort* __restrict__ w1Tl,
    ushort* __restrict__ w2Th, ushort* __restrict__ w2Tl,
    ushort* __restrict__ nbr)
{
    const int t = threadIdx.x;

    if (blockIdx.x >= GRID_SEL) {       // ---- weight preconversion blocks ----
        const int idx = (blockIdx.x - GRID_SEL) * 256 + t;
        if (idx < 128 * KP1) {
            const int n = idx / KP1, k = idx - n * KP1;
            const float v = (k < 78) ? w1[k * HID + n] : 0.0f;
            const __hip_bfloat16 h = __float2bfloat16(v);
            w1Th[idx] = __builtin_bit_cast(ushort, h);
            w1Tl[idx] = bfb(v - __bfloat162float(h));
        } else if (idx < CONV_ELEMS) {
            const int i = idx - 128 * KP1;
            const int n = i >> 7, k = i & 127;
            const float v = w2[k * HID + n];
            const __hip_bfloat16 h = __float2bfloat16(v);
            w2Th[i] = __builtin_bit_cast(ushort, h);
            w2Tl[i] = bfb(v - __bfloat162float(h));
        }
        return;
    }

    __shared__ uint histS[PPB][256];
    __shared__ unsigned long long survS[PPB][SURVCAP];
    __shared__ int  TS[PPB];
    __shared__ uint scntS[PPB];

    const int pid0 = blockIdx.x * PPB;
    const int b  = pid0 >> 10;
    const int nb = pid0 & (N - 1);
    const float* posb = pos + (size_t)b * N * 3;

#pragma unroll
    for (int p = 0; p < PPB; ++p) histS[p][t] = 0;
    if (t < PPB) scntS[t] = 0;

    float cx[PPB], cy[PPB], cz[PPB];
#pragma unroll
    for (int p = 0; p < PPB; ++p) {
        cx[p] = posb[(nb + p) * 3 + 0];
        cy[p] = posb[(nb + p) * 3 + 1];
        cz[p] = posb[(nb + p) * 3 + 2];
    }

    // phase 1: r2 for 4 particles x 4 candidates (candidate pos loads shared)
    float r2v[PPB][4];
#pragma unroll
    for (int q = 0; q < 4; ++q) {
        const int j = t + q * 256;
        const float px = posb[j * 3 + 0];
        const float py = posb[j * 3 + 1];
        const float pz = posb[j * 3 + 2];
#pragma unroll
        for (int p = 0; p < PPB; ++p) {
            const float dx = pbc(__fsub_rn(cx[p], px));
            const float dy = pbc(__fsub_rn(cy[p], py));
            const float dz = pbc(__fsub_rn(cz[p], pz));
            float r2 = __fadd_rn(__fadd_rn(__fmul_rn(dx, dx), __fmul_rn(dy, dy)),
                                 __fmul_rn(dz, dz));
            if (j == nb + p) r2 = 1e9f;
            r2v[p][q] = r2;
        }
    }
    __syncthreads();

    // phase 2: 4 histograms
#pragma unroll
    for (int p = 0; p < PPB; ++p)
#pragma unroll
        for (int q = 0; q < 4; ++q)
            atomicAdd(&histS[p][r2bin(__float_as_uint(r2v[p][q]))], 1u);
    __syncthreads();

    {   // wave p scans particle p's histogram for the rank-K bin
        const int p = t >> 6, lane = t & 63;
        const uint h0 = histS[p][4 * lane + 0], h1v = histS[p][4 * lane + 1];
        const uint h2v = histS[p][4 * lane + 2], h3v = histS[p][4 * lane + 3];
        const uint s = h0 + h1v + h2v + h3v;
        uint inc = s;
#pragma unroll
        for (int off = 1; off < 64; off <<= 1) {
            const uint v = __shfl_up(inc, off, 64);
            if (lane >= off) inc += v;
        }
        const uint exc = inc - s;
        if (exc < (uint)K && inc >= (uint)K) {
            uint c = exc; int Tb = -1;
            c += h0;  if (Tb < 0 && c >= (uint)K) Tb = 4 * lane + 0;
            c += h1v; if (Tb < 0 && c >= (uint)K) Tb = 4 * lane + 1;
            c += h2v; if (Tb < 0 && c >= (uint)K) Tb = 4 * lane + 2;
            c += h3v; if (Tb < 0 && c >= (uint)K) Tb = 4 * lane + 3;
            TS[p] = Tb;
        }
    }
    __syncthreads();

    // compact survivors per particle
#pragma unroll
    for (int p = 0; p < PPB; ++p) {
        const uint T = (uint)TS[p];
#pragma unroll
        for (int q = 0; q < 4; ++q) {
            const uint key = __float_as_uint(r2v[p][q]);
            if (r2bin(key) <= T) {
                const uint pp = atomicAdd(&scntS[p], 1u);
                if (pp < (uint)SURVCAP)
                    survS[p][pp] =
                        ((unsigned long long)key << 32) | (uint)(t + q * 256);
            }
        }
    }
    __syncthreads();

    {   // exact rank by counting; order == lax.top_k (r2 asc, idx asc)
        const int p = t >> 6;
        const int S = min((int)scntS[p], SURVCAP);
#pragma unroll
        for (int half = 0; half < 2; ++half) {
            const int s = (t & 63) + half * 64;
            if (s < S) {
                const unsigned long long me = survS[p][s];
                int rank = 0;
                for (int jj = 0; jj < S; ++jj) rank += (survS[p][jj] < me) ? 1 : 0;
                if (rank < K)
                    nbr[(size_t)(pid0 + p) * K + rank] = (ushort)(me & 0xffffULL);
            }
        }
    }
}

// ---- kernel 2: features (80 rows) + MFMA MLP (M=80) + in-register maxpool.
__global__ __launch_bounds__(256, 4) void mlp_kernel(
    const float* __restrict__ pos, const float* __restrict__ ori,
    const float* __restrict__ b1, const float* __restrict__ b2,
    const float* __restrict__ w3, const float* __restrict__ b3,
    const ushort* __restrict__ w1Th, const ushort* __restrict__ w1Tl,
    const ushort* __restrict__ w2Th, const ushort* __restrict__ w2Tl,
    const ushort* __restrict__ nbr, float* __restrict__ out)
{
    __shared__ __align__(16) __hip_bfloat16 fS[MROWS][FP];
    __shared__ __align__(16) ushort h1S[MROWS][H1P];
    __shared__ float RpS[PPB][9];
    __shared__ float red[4][PPB];

    const int pid0 = blockIdx.x * PPB;
    const int b  = pid0 >> 10;
    const int nb = pid0 & (N - 1);
    const int t  = threadIdx.x;
    const float* posb = pos + (size_t)b * N * 3;
    const float* orib = ori + (size_t)b * N * 9;

    if (t < PPB * 9) RpS[t / 9][t % 9] = orib[(size_t)(nb + t / 9) * 9 + (t % 9)];
    __syncthreads();

    // features: 80 lanes, p = t/20, k = t%20
    if (t < PPB * K) {
        const int p = t / K, k = t - p * K;
        const int j = (int)nbr[(size_t)(pid0 + p) * K + k];
        float Rp[9], Rn[9];
#pragma unroll
        for (int q = 0; q < 9; ++q) Rp[q] = RpS[p][q];
#pragma unroll
        for (int q = 0; q < 9; ++q) Rn[q] = orib[(size_t)j * 9 + q];

        const float cxp = posb[(nb + p) * 3 + 0];
        const float cyp = posb[(nb + p) * 3 + 1];
        const float czp = posb[(nb + p) * 3 + 2];
        const float dx = pbc(__fsub_rn(cxp, posb[j * 3 + 0]));
        const float dy = pbc(__fsub_rn(cyp, posb[j * 3 + 1]));
        const float dz = pbc(__fsub_rn(czp, posb[j * 3 + 2]));
        const float r2 = __fadd_rn(__fadd_rn(__fmul_rn(dx, dx), __fmul_rn(dy, dy)),
                                   __fmul_rn(dz, dz));
        const float r = sqrtf(r2);
        const float invr = 1.0f / r;
        const float ux = dx * invr, uy = dy * invr, uz = dz * invr;

        __hip_bfloat16* f = fS[p * K + k];
        f[0] = __float2bfloat16(r);
        f[1] = __float2bfloat16(invr);
        f[2] = __float2bfloat16(ux);
        f[3] = __float2bfloat16(uy);
        f[4] = __float2bfloat16(uz);

        float diag[3];
#pragma unroll
        for (int i = 0; i < 3; ++i) {
#pragma unroll
            for (int l = 0; l < 3; ++l) {
                float s = 0.0f, en2 = 0.0f;
#pragma unroll
                for (int m = 0; m < 3; ++m) {
                    const float e = Rp[i * 3 + m] * Rn[l * 3 + m];
                    f[14 + i * 9 + l * 3 + m] = __float2bfloat16(e);
                    en2 += e * e;
                    s += e;
                }
                f[5 + i * 3 + l] = __float2bfloat16(s);
                f[41 + i * 3 + l] = __float2bfloat16(sqrtf(en2));
                float rr = 0.0f;
#pragma unroll
                for (int m = 0; m < 3; ++m) rr += Rp[m * 3 + i] * Rn[m * 3 + l];
                f[62 + i * 3 + l] = __float2bfloat16(rr);
                if (i == l) diag[i] = rr;
            }
        }
#pragma unroll
        for (int i = 0; i < 3; ++i) {
            const float ax = Rp[i * 3 + 0], ay = Rp[i * 3 + 1], az = Rp[i * 3 + 2];
            const float bx = Rn[i * 3 + 0], by = Rn[i * 3 + 1], bz = Rn[i * 3 + 2];
            const float ccx = ay * bz - az * by;
            const float ccy = az * bx - ax * bz;
            const float ccz = ax * by - ay * bx;
            f[50 + i * 3 + 0] = __float2bfloat16(ccx);
            f[50 + i * 3 + 1] = __float2bfloat16(ccy);
            f[50 + i * 3 + 2] = __float2bfloat16(ccz);
            f[59 + i] = __float2bfloat16(sqrtf(ccx * ccx + ccy * ccy + ccz * ccz));
            const float dp = ux * ax + uy * ay + uz * az;
            f[71 + i] = __float2bfloat16(__expf(-dp * dp));
            const float dn = ux * bx + uy * by + uz * bz;
            f[74 + i] = __float2bfloat16(__expf(-dn * dn));
        }
        const float tr = diag[0] + diag[1] + diag[2];
        float ca = (tr - 1.0f) * 0.5f;
        ca = fminf(fmaxf(ca, -1.0f + 1e-6f), 1.0f - 1e-6f);
        f[77] = __float2bfloat16(acosf(ca));
#pragma unroll
        for (int i = 78; i < KP1; ++i) f[i] = __float2bfloat16(0.0f);
    }
    __syncthreads();

    // MFMA MLP: wave wv owns cols [32wv,32wv+32); M = 80 (5 m-tiles)
    const int wv = t >> 6, ln = t & 63;
    const int lr = ln & 15, lg = ln >> 4;
    const int n0 = wv * 32 + lr, n1 = n0 + 16;

    f32x4 acc[MT][2];
    {
        const float bb0 = b1[n0], bb1 = b1[n1];
#pragma unroll
        for (int mt = 0; mt < MT; ++mt) {
            acc[mt][0] = f32x4{bb0, bb0, bb0, bb0};
            acc[mt][1] = f32x4{bb1, bb1, bb1, bb1};
        }
    }
    {
        const ushort* pb0h = w1Th + n0 * KP1 + lg * 8;
        const ushort* pb0l = w1Tl + n0 * KP1 + lg * 8;
        const ushort* pb1h = w1Th + n1 * KP1 + lg * 8;
        const ushort* pb1l = w1Tl + n1 * KP1 + lg * 8;
#pragma unroll
        for (int ks = 0; ks < 3; ++ks) {
            const short8 b0h = *reinterpret_cast<const short8*>(pb0h + ks * 32);
            const short8 b0l = *reinterpret_cast<const short8*>(pb0l + ks * 32);
            const short8 b1h = *reinterpret_cast<const short8*>(pb1h + ks * 32);
            const short8 b1l = *reinterpret_cast<const short8*>(pb1l + ks * 32);
#pragma unroll
            for (int mt = 0; mt < MT; ++mt) {
                const short8 a = *reinterpret_cast<const short8*>(
                    &fS[16 * mt + lr][ks * 32 + lg * 8]);
                acc[mt][0] = __builtin_amdgcn_mfma_f32_16x16x32_bf16(a, b0h, acc[mt][0], 0, 0, 0);
                acc[mt][0] = __builtin_amdgcn_mfma_f32_16x16x32_bf16(a, b0l, acc[mt][0], 0, 0, 0);
                acc[mt][1] = __builtin_amdgcn_mfma_f32_16x16x32_bf16(a, b1h, acc[mt][1], 0, 0, 0);
                acc[mt][1] = __builtin_amdgcn_mfma_f32_16x16x32_bf16(a, b1l, acc[mt][1], 0, 0, 0);
            }
        }
    }
#pragma unroll
    for (int mt = 0; mt < MT; ++mt)
#pragma unroll
        for (int r = 0; r < 4; ++r) {
            h1S[16 * mt + 4 * lg + r][n0] = bfb(tanh_f(acc[mt][0][r]));
            h1S[16 * mt + 4 * lg + r][n1] = bfb(tanh_f(acc[mt][1][r]));
        }
    __syncthreads();

    // layer 2: K = 128
    {
        const float bb0 = b2[n0], bb1 = b2[n1];
#pragma unroll
        for (int mt = 0; mt < MT; ++mt) {
            acc[mt][0] = f32x4{bb0, bb0, bb0, bb0};
            acc[mt][1] = f32x4{bb1, bb1, bb1, bb1};
        }
    }
    {
        const ushort* pb0h = w2Th + n0 * HID + lg * 8;
        const ushort* pb0l = w2Tl + n0 * HID + lg * 8;
        const ushort* pb1h = w2Th + n1 * HID + lg * 8;
        const ushort* pb1l = w2Tl + n1 * HID + lg * 8;
#pragma unroll
        for (int ks = 0; ks < 4; ++ks) {
            const short8 b0h = *reinterpret_cast<const short8*>(pb0h + ks * 32);
            const short8 b0l = *reinterpret_cast<const short8*>(pb0l + ks * 32);
            const short8 b1h = *reinterpret_cast<const short8*>(pb1h + ks * 32);
            const short8 b1l = *reinterpret_cast<const short8*>(pb1l + ks * 32);
#pragma unroll
            for (int mt = 0; mt < MT; ++mt) {
                const short8 a = *reinterpret_cast<const short8*>(
                    &h1S[16 * mt + lr][ks * 32 + lg * 8]);
                acc[mt][0] = __builtin_amdgcn_mfma_f32_16x16x32_bf16(a, b0h, acc[mt][0], 0, 0, 0);
                acc[mt][0] = __builtin_amdgcn_mfma_f32_16x16x32_bf16(a, b0l, acc[mt][0], 0, 0, 0);
                acc[mt][1] = __builtin_amdgcn_mfma_f32_16x16x32_bf16(a, b1h, acc[mt][1], 0, 0, 0);
                acc[mt][1] = __builtin_amdgcn_mfma_f32_16x16x32_bf16(a, b1l, acc[mt][1], 0, 0, 0);
            }
        }
    }

    // epilogue: tanh, masked per-particle maxpool, dot w3
#pragma unroll
    for (int mt = 0; mt < MT; ++mt)
#pragma unroll
        for (int nt = 0; nt < 2; ++nt)
#pragma unroll
            for (int r = 0; r < 4; ++r) acc[mt][nt][r] = tanh_f(acc[mt][nt][r]);

    const float w3n0 = w3[n0], w3n1 = w3[n1];
#pragma unroll
    for (int p = 0; p < PPB; ++p) {
        float m0 = -3.0e38f, m1 = -3.0e38f;
#pragma unroll
        for (int mt = 0; mt < MT; ++mt) {
            const bool in = (uint)(4 * mt + lg - 5 * p) < 5u;
#pragma unroll
            for (int r = 0; r < 4; ++r) {
                m0 = fmaxf(m0, in ? acc[mt][0][r] : -3.0e38f);
                m1 = fmaxf(m1, in ? acc[mt][1][r] : -3.0e38f);
            }
        }
        m0 = fmaxf(m0, __shfl_xor(m0, 16, 64));
        m0 = fmaxf(m0, __shfl_xor(m0, 32, 64));
        m1 = fmaxf(m1, __shfl_xor(m1, 16, 64));
        m1 = fmaxf(m1, __shfl_xor(m1, 32, 64));
        float v = m0 * w3n0 + m1 * w3n1;
#pragma unroll
        for (int off = 1; off < 16; off <<= 1) v += __shfl_xor(v, off, 64);
        if (ln == 0) red[wv][p] = v;
    }
    __syncthreads();
    if (t < PPB) out[pid0 + t] = red[0][t] + red[1][t] + red[2][t] + red[3][t] + b3[0];
}

} // namespace

extern "C" void kernel_launch(void* const* d_in, const int* in_sizes, int n_in,
                              void* d_out, int out_size, void* d_ws, size_t ws_size,
                              hipStream_t stream) {
    const float* pos = (const float*)d_in[0];
    const float* ori = (const float*)d_in[1];
    const float* w1  = (const float*)d_in[2];
    const float* b1  = (const float*)d_in[3];
    const float* w2  = (const float*)d_in[4];
    const float* b2  = (const float*)d_in[5];
    const float* w3  = (const float*)d_in[6];
    const float* b3  = (const float*)d_in[7];
    float* out = (float*)d_out;

    // ws: w1T hi/lo (12288 ea), w2T hi/lo (16384 ea) = 57344 ushorts (114688 B),
    // then nbr = B*N*K ushorts (655360 B). Total ~770 KB.
    ushort* w1Th = (ushort*)d_ws;
    ushort* w1Tl = w1Th + 128 * KP1;
    ushort* w2Th = w1Tl + 128 * KP1;
    ushort* w2Tl = w2Th + 128 * 128;
    ushort* nbr  = w2Tl + 128 * 128;

    select_kernel<<<dim3(GRID_SEL + GRID_CONV), dim3(256), 0, stream>>>(
        pos, w1, w2, w1Th, w1Tl, w2Th, w2Tl, nbr);
    mlp_kernel<<<dim3(GRID_SEL), dim3(256), 0, stream>>>(
        pos, ori, b1, b2, w3, b3, w1Th, w1Tl, w2Th, w2Tl, nbr, out);
}

// Round 13
// 165.781 us; speedup vs baseline: 3.9080x; 1.0127x over previous
//
#include <hip/hip_runtime.h>
#include <hip/hip_bf16.h>

namespace {

constexpr int B = 16;
constexpr int N = 1024;
constexpr int K = 20;
constexpr int HID = 128;
constexpr float BOX = 10.0f;

constexpr int PPB = 4;                  // particles per block
constexpr int MROWS = PPB * K;          // 80 = 5 m-tiles exactly
constexpr int MT = 5;
constexpr int KP1 = 96;                 // layer-1 K padded 78 -> 96
constexpr int FP = 104;                 // fS row pitch (bf16); 208B rows (16B mult)
constexpr int H1P = 136;                // h1 row pitch (bf16); 272B rows (16B mult)
constexpr int SURVCAP = 128;
constexpr int NTHR = 8;

// radius ladder: r = 1.25 + 0.5i (i<7), last = catch-all (max possible r2 = 75)
constexpr float THRC[NTHR] = {1.5625f, 3.0625f, 5.0625f, 7.5625f,
                              10.5625f, 14.0625f, 18.0625f, 76.0f};

constexpr int GRID_SEL  = B * N / PPB;              // 4096
constexpr int CONV_ELEMS = 128 * KP1 + 128 * 128;   // 28672
constexpr int GRID_CONV = (CONV_ELEMS + 255) / 256; // 112

typedef __attribute__((ext_vector_type(8))) short short8;
typedef __attribute__((ext_vector_type(4))) float f32x4;

__device__ __forceinline__ float tanh_f(float x) {
    float e = __expf(2.0f * x);
    return 1.0f - 2.0f / (e + 1.0f);
}

__device__ __forceinline__ ushort bfb(float x) {
    __hip_bfloat16 h = __float2bfloat16(x);
    return __builtin_bit_cast(ushort, h);
}

// Exact min-image for |d| < 10: rint(fl(d/10)) == (d>5) - (d<-5).  (Sterbenz)
__device__ __forceinline__ float pbc(float d) {
    const float hi = __fsub_rn(d, BOX);
    const float lo = __fadd_rn(d, BOX);
    return d > 5.0f ? hi : (d < -5.0f ? lo : d);
}

// ---- kernel 1: 20-NN selection (ballot threshold-ladder, atomic-light) +
// weight conversion in trailing blocks. nbr written as ushort (idx < 1024).
__global__ __launch_bounds__(256, 8) void select_kernel(
    const float* __restrict__ pos,
    const float* __restrict__ w1, const float* __restrict__ w2,
    ushort* __restrict__ w1Th, ushort* __restrict__ w1Tl,
    ushort* __restrict__ w2Th, ushort* __restrict__ w2Tl,
    ushort* __restrict__ nbr)
{
    const int t = threadIdx.x;

    if (blockIdx.x >= GRID_SEL) {       // ---- weight preconversion blocks ----
        const int idx = (blockIdx.x - GRID_SEL) * 256 + t;
        if (idx < 128 * KP1) {
            const int n = idx / KP1, k = idx - n * KP1;
            const float v = (k < 78) ? w1[k * HID + n] : 0.0f;
            const __hip_bfloat16 h = __float2bfloat16(v);
            w1Th[idx] = __builtin_bit_cast(ushort, h);
            w1Tl[idx] = bfb(v - __bfloat162float(h));
        } else if (idx < CONV_ELEMS) {
            const int i = idx - 128 * KP1;
            const int n = i >> 7, k = i & 127;
            const float v = w2[k * HID + n];
            const __hip_bfloat16 h = __float2bfloat16(v);
            w2Th[i] = __builtin_bit_cast(ushort, h);
            w2Tl[i] = bfb(v - __bfloat162float(h));
        }
        return;
    }

    __shared__ ushort cntS[4][PPB][NTHR];       // [wave][particle][thr]
    __shared__ unsigned long long survS[PPB][SURVCAP];
    __shared__ float thrS[PPB];
    __shared__ uint  scntS[PPB];

    const int pid0 = blockIdx.x * PPB;
    const int b  = pid0 >> 10;
    const int nb = pid0 & (N - 1);
    const float* posb = pos + (size_t)b * N * 3;

    if (t < PPB) scntS[t] = 0;

    float cx[PPB], cy[PPB], cz[PPB];
#pragma unroll
    for (int p = 0; p < PPB; ++p) {
        cx[p] = posb[(nb + p) * 3 + 0];
        cy[p] = posb[(nb + p) * 3 + 1];
        cz[p] = posb[(nb + p) * 3 + 2];
    }

    // phase 1: r2 for 4 particles x 4 candidates (candidate pos loads shared)
    float r2v[PPB][4];
#pragma unroll
    for (int q = 0; q < 4; ++q) {
        const int j = t + q * 256;
        const float px = posb[j * 3 + 0];
        const float py = posb[j * 3 + 1];
        const float pz = posb[j * 3 + 2];
#pragma unroll
        for (int p = 0; p < PPB; ++p) {
            const float dx = pbc(__fsub_rn(cx[p], px));
            const float dy = pbc(__fsub_rn(cy[p], py));
            const float dz = pbc(__fsub_rn(cz[p], pz));
            float r2 = __fadd_rn(__fadd_rn(__fmul_rn(dx, dx), __fmul_rn(dy, dy)),
                                 __fmul_rn(dz, dz));
            if (j == nb + p) r2 = 1e9f;     // self-exclude: never below any THR
            r2v[p][q] = r2;
        }
    }

    // phase 2: per-wave ballot counts for each (particle, threshold)
    {
        const int wv = t >> 6, lane = t & 63;
#pragma unroll
        for (int p = 0; p < PPB; ++p) {
#pragma unroll
            for (int i = 0; i < NTHR; ++i) {
                uint c = 0;
#pragma unroll
                for (int q = 0; q < 4; ++q)
                    c += (uint)__popcll(__ballot(r2v[p][q] < THRC[i]));
                if (lane == 0) cntS[wv][p][i] = (ushort)c;
            }
        }
    }
    __syncthreads();

    {   // wave p: pick first threshold with total count >= K
        const int p = t >> 6, lane = t & 63;
        uint tot = 0;
        float thrv = 0.0f;
        if (lane < NTHR) {
            tot = (uint)cntS[0][p][lane] + cntS[1][p][lane]
                + (uint)cntS[2][p][lane] + cntS[3][p][lane];
            // per-lane threshold constant (compile-time unrolled select)
#pragma unroll
            for (int i = 0; i < NTHR; ++i) if (lane == i) thrv = THRC[i];
        }
        const unsigned long long m = __ballot(lane < NTHR && tot >= (uint)K);
        const int sel = __ffsll((long long)m) - 1;
        if (lane == sel) thrS[p] = thrv;
    }
    __syncthreads();

    // compact survivors (r2 < chosen thr); order irrelevant (exact rank later)
#pragma unroll
    for (int p = 0; p < PPB; ++p) {
        const float thr = thrS[p];
#pragma unroll
        for (int q = 0; q < 4; ++q) {
            if (r2v[p][q] < thr) {
                const uint pp = atomicAdd(&scntS[p], 1u);
                if (pp < (uint)SURVCAP)
                    survS[p][pp] = ((unsigned long long)__float_as_uint(r2v[p][q]) << 32)
                                   | (uint)(t + q * 256);
            }
        }
    }
    __syncthreads();

    {   // exact rank by counting; order == lax.top_k (r2 asc, idx asc)
        const int p = t >> 6;
        const int S = min((int)scntS[p], SURVCAP);
#pragma unroll
        for (int half = 0; half < 2; ++half) {
            const int s = (t & 63) + half * 64;
            if (s < S) {
                const unsigned long long me = survS[p][s];
                int rank = 0;
                for (int jj = 0; jj < S; ++jj) rank += (survS[p][jj] < me) ? 1 : 0;
                if (rank < K)
                    nbr[(size_t)(pid0 + p) * K + rank] = (ushort)(me & 0xffffULL);
            }
        }
    }
}

// ---- kernel 2: features (80 rows) + MFMA MLP (M=80) + in-register maxpool.
// fS and h1S share one LDS buffer (disjoint lifetimes) -> ~22 KB -> 7 blocks/CU.
__global__ __launch_bounds__(256, 7) void mlp_kernel(
    const float* __restrict__ pos, const float* __restrict__ ori,
    const float* __restrict__ b1, const float* __restrict__ b2,
    const float* __restrict__ w3, const float* __restrict__ b3,
    const ushort* __restrict__ w1Th, const ushort* __restrict__ w1Tl,
    const ushort* __restrict__ w2Th, const ushort* __restrict__ w2Tl,
    const ushort* __restrict__ nbr, float* __restrict__ out)
{
    __shared__ __align__(16) char uS[MROWS * H1P * 2];   // max(fS, h1S) bytes
    __hip_bfloat16 (*const fS)[FP] = (__hip_bfloat16 (*)[FP])uS;
    ushort (*const h1S)[H1P] = (ushort (*)[H1P])uS;
    __shared__ float RpS[PPB][9];
    __shared__ float red[4][PPB];

    const int pid0 = blockIdx.x * PPB;
    const int b  = pid0 >> 10;
    const int nb = pid0 & (N - 1);
    const int t  = threadIdx.x;
    const float* posb = pos + (size_t)b * N * 3;
    const float* orib = ori + (size_t)b * N * 9;

    if (t < PPB * 9) RpS[t / 9][t % 9] = orib[(size_t)(nb + t / 9) * 9 + (t % 9)];
    __syncthreads();

    // features: 80 lanes, p = t/20, k = t%20
    if (t < PPB * K) {
        const int p = t / K, k = t - p * K;
        const int j = (int)nbr[(size_t)(pid0 + p) * K + k];
        float Rp[9], Rn[9];
#pragma unroll
        for (int q = 0; q < 9; ++q) Rp[q] = RpS[p][q];
#pragma unroll
        for (int q = 0; q < 9; ++q) Rn[q] = orib[(size_t)j * 9 + q];

        const float cxp = posb[(nb + p) * 3 + 0];
        const float cyp = posb[(nb + p) * 3 + 1];
        const float czp = posb[(nb + p) * 3 + 2];
        const float dx = pbc(__fsub_rn(cxp, posb[j * 3 + 0]));
        const float dy = pbc(__fsub_rn(cyp, posb[j * 3 + 1]));
        const float dz = pbc(__fsub_rn(czp, posb[j * 3 + 2]));
        const float r2 = __fadd_rn(__fadd_rn(__fmul_rn(dx, dx), __fmul_rn(dy, dy)),
                                   __fmul_rn(dz, dz));
        const float r = sqrtf(r2);
        const float invr = 1.0f / r;
        const float ux = dx * invr, uy = dy * invr, uz = dz * invr;

        __hip_bfloat16* f = fS[p * K + k];
        f[0] = __float2bfloat16(r);
        f[1] = __float2bfloat16(invr);
        f[2] = __float2bfloat16(ux);
        f[3] = __float2bfloat16(uy);
        f[4] = __float2bfloat16(uz);

        float diag[3];
#pragma unroll
        for (int i = 0; i < 3; ++i) {
#pragma unroll
            for (int l = 0; l < 3; ++l) {
                float s = 0.0f, en2 = 0.0f;
#pragma unroll
                for (int m = 0; m < 3; ++m) {
                    const float e = Rp[i * 3 + m] * Rn[l * 3 + m];
                    f[14 + i * 9 + l * 3 + m] = __float2bfloat16(e);
                    en2 += e * e;
                    s += e;
                }
                f[5 + i * 3 + l] = __float2bfloat16(s);
                f[41 + i * 3 + l] = __float2bfloat16(sqrtf(en2));
                float rr = 0.0f;
#pragma unroll
                for (int m = 0; m < 3; ++m) rr += Rp[m * 3 + i] * Rn[m * 3 + l];
                f[62 + i * 3 + l] = __float2bfloat16(rr);
                if (i == l) diag[i] = rr;
            }
        }
#pragma unroll
        for (int i = 0; i < 3; ++i) {
            const float ax = Rp[i * 3 + 0], ay = Rp[i * 3 + 1], az = Rp[i * 3 + 2];
            const float bx = Rn[i * 3 + 0], by = Rn[i * 3 + 1], bz = Rn[i * 3 + 2];
            const float ccx = ay * bz - az * by;
            const float ccy = az * bx - ax * bz;
            const float ccz = ax * by - ay * bx;
            f[50 + i * 3 + 0] = __float2bfloat16(ccx);
            f[50 + i * 3 + 1] = __float2bfloat16(ccy);
            f[50 + i * 3 + 2] = __float2bfloat16(ccz);
            f[59 + i] = __float2bfloat16(sqrtf(ccx * ccx + ccy * ccy + ccz * ccz));
            const float dp = ux * ax + uy * ay + uz * az;
            f[71 + i] = __float2bfloat16(__expf(-dp * dp));
            const float dn = ux * bx + uy * by + uz * bz;
            f[74 + i] = __float2bfloat16(__expf(-dn * dn));
        }
        const float tr = diag[0] + diag[1] + diag[2];
        float ca = (tr - 1.0f) * 0.5f;
        ca = fminf(fmaxf(ca, -1.0f + 1e-6f), 1.0f - 1e-6f);
        f[77] = __float2bfloat16(acosf(ca));
#pragma unroll
        for (int i = 78; i < KP1; ++i) f[i] = __float2bfloat16(0.0f);
    }
    __syncthreads();

    // MFMA MLP: wave wv owns cols [32wv,32wv+32); M = 80 (5 m-tiles)
    const int wv = t >> 6, ln = t & 63;
    const int lr = ln & 15, lg = ln >> 4;
    const int n0 = wv * 32 + lr, n1 = n0 + 16;

    f32x4 acc[MT][2];
    {
        const float bb0 = b1[n0], bb1 = b1[n1];
#pragma unroll
        for (int mt = 0; mt < MT; ++mt) {
            acc[mt][0] = f32x4{bb0, bb0, bb0, bb0};
            acc[mt][1] = f32x4{bb1, bb1, bb1, bb1};
        }
    }
    {
        const ushort* pb0h = w1Th + n0 * KP1 + lg * 8;
        const ushort* pb0l = w1Tl + n0 * KP1 + lg * 8;
        const ushort* pb1h = w1Th + n1 * KP1 + lg * 8;
        const ushort* pb1l = w1Tl + n1 * KP1 + lg * 8;
#pragma unroll
        for (int ks = 0; ks < 3; ++ks) {
            const short8 b0h = *reinterpret_cast<const short8*>(pb0h + ks * 32);
            const short8 b0l = *reinterpret_cast<const short8*>(pb0l + ks * 32);
            const short8 b1h = *reinterpret_cast<const short8*>(pb1h + ks * 32);
            const short8 b1l = *reinterpret_cast<const short8*>(pb1l + ks * 32);
#pragma unroll
            for (int mt = 0; mt < MT; ++mt) {
                const short8 a = *reinterpret_cast<const short8*>(
                    &fS[16 * mt + lr][ks * 32 + lg * 8]);
                acc[mt][0] = __builtin_amdgcn_mfma_f32_16x16x32_bf16(a, b0h, acc[mt][0], 0, 0, 0);
                acc[mt][0] = __builtin_amdgcn_mfma_f32_16x16x32_bf16(a, b0l, acc[mt][0], 0, 0, 0);
                acc[mt][1] = __builtin_amdgcn_mfma_f32_16x16x32_bf16(a, b1h, acc[mt][1], 0, 0, 0);
                acc[mt][1] = __builtin_amdgcn_mfma_f32_16x16x32_bf16(a, b1l, acc[mt][1], 0, 0, 0);
            }
        }
    }
    __syncthreads();    // union aliasing: ALL fS reads must complete before h1 writes
#pragma unroll
    for (int mt = 0; mt < MT; ++mt)
#pragma unroll
        for (int r = 0; r < 4; ++r) {
            h1S[16 * mt + 4 * lg + r][n0] = bfb(tanh_f(acc[mt][0][r]));
            h1S[16 * mt + 4 * lg + r][n1] = bfb(tanh_f(acc[mt][1][r]));
        }
    __syncthreads();

    // layer 2: K = 128
    {
        const float bb0 = b2[n0], bb1 = b2[n1];
#pragma unroll
        for (int mt = 0; mt < MT; ++mt) {
            acc[mt][0] = f32x4{bb0, bb0, bb0, bb0};
            acc[mt][1] = f32x4{bb1, bb1, bb1, bb1};
        }
    }
    {
        const ushort* pb0h = w2Th + n0 * HID + lg * 8;
        const ushort* pb0l = w2Tl + n0 * HID + lg * 8;
        const ushort* pb1h = w2Th + n1 * HID + lg * 8;
        const ushort* pb1l = w2Tl + n1 * HID + lg * 8;
#pragma unroll
        for (int ks = 0; ks < 4; ++ks) {
            const short8 b0h = *reinterpret_cast<const short8*>(pb0h + ks * 32);
            const short8 b0l = *reinterpret_cast<const short8*>(pb0l + ks * 32);
            const short8 b1h = *reinterpret_cast<const short8*>(pb1h + ks * 32);
            const short8 b1l = *reinterpret_cast<const short8*>(pb1l + ks * 32);
#pragma unroll
            for (int mt = 0; mt < MT; ++mt) {
                const short8 a = *reinterpret_cast<const short8*>(
                    &h1S[16 * mt + lr][ks * 32 + lg * 8]);
                acc[mt][0] = __builtin_amdgcn_mfma_f32_16x16x32_bf16(a, b0h, acc[mt][0], 0, 0, 0);
                acc[mt][0] = __builtin_amdgcn_mfma_f32_16x16x32_bf16(a, b0l, acc[mt][0], 0, 0, 0);
                acc[mt][1] = __builtin_amdgcn_mfma_f32_16x16x32_bf16(a, b1h, acc[mt][1], 0, 0, 0);
                acc[mt][1] = __builtin_amdgcn_mfma_f32_16x16x32_bf16(a, b1l, acc[mt][1], 0, 0, 0);
            }
        }
    }

    // epilogue: tanh, masked per-particle maxpool, dot w3
#pragma unroll
    for (int mt = 0; mt < MT; ++mt)
#pragma unroll
        for (int nt = 0; nt < 2; ++nt)
#pragma unroll
            for (int r = 0; r < 4; ++r) acc[mt][nt][r] = tanh_f(acc[mt][nt][r]);

    const float w3n0 = w3[n0], w3n1 = w3[n1];
#pragma unroll
    for (int p = 0; p < PPB; ++p) {
        float m0 = -3.0e38f, m1 = -3.0e38f;
#pragma unroll
        for (int mt = 0; mt < MT; ++mt) {
            const bool in = (uint)(4 * mt + lg - 5 * p) < 5u;
#pragma unroll
            for (int r = 0; r < 4; ++r) {
                m0 = fmaxf(m0, in ? acc[mt][0][r] : -3.0e38f);
                m1 = fmaxf(m1, in ? acc[mt][1][r] : -3.0e38f);
            }
        }
        m0 = fmaxf(m0, __shfl_xor(m0, 16, 64));
        m0 = fmaxf(m0, __shfl_xor(m0, 32, 64));
        m1 = fmaxf(m1, __shfl_xor(m1, 16, 64));
        m1 = fmaxf(m1, __shfl_xor(m1, 32, 64));
        float v = m0 * w3n0 + m1 * w3n1;
#pragma unroll
        for (int off = 1; off < 16; off <<= 1) v += __shfl_xor(v, off, 64);
        if (ln == 0) red[wv][p] = v;
    }
    __syncthreads();
    if (t < PPB) out[pid0 + t] = red[0][t] + red[1][t] + red[2][t] + red[3][t] + b3[0];
}

} // namespace

extern "C" void kernel_launch(void* const* d_in, const int* in_sizes, int n_in,
                              void* d_out, int out_size, void* d_ws, size_t ws_size,
                              hipStream_t stream) {
    const float* pos = (const float*)d_in[0];
    const float* ori = (const float*)d_in[1];
    const float* w1  = (const float*)d_in[2];
    const float* b1  = (const float*)d_in[3];
    const float* w2  = (const float*)d_in[4];
    const float* b2  = (const float*)d_in[5];
    const float* w3  = (const float*)d_in[6];
    const float* b3  = (const float*)d_in[7];
    float* out = (float*)d_out;

    // ws: w1T hi/lo (12288 ea), w2T hi/lo (16384 ea) = 57344 ushorts (114688 B),
    // then nbr = B*N*K ushorts (655360 B). Total ~770 KB.
    ushort* w1Th = (ushort*)d_ws;
    ushort* w1Tl = w1Th + 128 * KP1;
    ushort* w2Th = w1Tl + 128 * KP1;
    ushort* w2Tl = w2Th + 128 * 128;
    ushort* nbr  = w2Tl + 128 * 128;

    select_kernel<<<dim3(GRID_SEL + GRID_CONV), dim3(256), 0, stream>>>(
        pos, w1, w2, w1Th, w1Tl, w2Th, w2Tl, nbr);
    mlp_kernel<<<dim3(GRID_SEL), dim3(256), 0, stream>>>(
        pos, ori, b1, b2, w3, b3, w1Th, w1Tl, w2Th, w2Tl, nbr, out);
}